// Round 10
// baseline (311.618 us; speedup 1.0000x reference)
//
#include <hip/hip_runtime.h>
#include <math.h>

#define EPSV 1e-5f
#define EPB3 4096  // edges per bucket-pass block (196 blocks, proven config)
#define NBP 256    // buckets of 256 nodes (N <= 65536; src packed in 16 bits)
#define CAP 6144   // per-bucket edgeTmp slab capacity (mean ~4081, +32 sigma)
#define CAPS (CAP + 768)  // padded sorted-slab capacity (pad <=3 per node)

typedef short s16x8 __attribute__((ext_vector_type(8)));
typedef float f32x4 __attribute__((ext_vector_type(4)));
typedef unsigned short u16;
typedef unsigned short u16x4 __attribute__((ext_vector_type(4)));

#define MFMA(a, b, c) __builtin_amdgcn_mfma_f32_16x16x32_bf16(a, b, c, 0, 0, 0)

__device__ inline u16 f2bf(float f) {
    unsigned u = __float_as_uint(f);
    return (u16)((u + 0x7FFF + ((u >> 16) & 1)) >> 16);
}
__device__ inline float bf2f(u16 h) { return __uint_as_float(((unsigned)h) << 16); }

__device__ inline void split8(const float4& a, const float4& b, s16x8& hv, s16x8& lv) {
    float f[8] = {a.x, a.y, a.z, a.w, b.x, b.y, b.z, b.w};
#pragma unroll
    for (int i = 0; i < 8; ++i) {
        u16 h = f2bf(f[i]);
        hv[i] = (short)h;
        lv[i] = (short)f2bf(f[i] - bf2f(h));
    }
}

// ---------------- pre1: bucket partition + weight prep (merged) ----------------
__global__ __launch_bounds__(512) void k_pre1(
    const int* __restrict__ src, const int* __restrict__ dst, int E,
    int* __restrict__ bucketCursor, unsigned* __restrict__ edgeTmp,
    const float* __restrict__ pre_w, const float* __restrict__ post_w,
    const float* __restrict__ post_b, const float* __restrict__ lin_w,
    const float* __restrict__ lin_b, u16* __restrict__ WpT_hi,
    u16* __restrict__ WpT_lo, u16* __restrict__ WT_hi, u16* __restrict__ WT_lo,
    float* __restrict__ bpp, int NB1) {
    __shared__ int cnt[NBP], loff[NBP], lpos[NBP], gbase[NBP], sbuf[NBP];
    __shared__ unsigned stage[EPB3];
    int t = threadIdx.x;
    if ((int)blockIdx.x < NB1) {
        int base = blockIdx.x * EPB3;
        int cntE = min(EPB3, E - base);
        if (t < NBP) cnt[t] = 0;
        __syncthreads();
        unsigned ed[8];
#pragma unroll
        for (int j = 0; j < 8; ++j) {
            int idx = j * 512 + t;
            if (idx < cntE) {
                int e = base + idx;
                unsigned s = (unsigned)src[e];
                unsigned d = (unsigned)dst[e];
                ed[j] = ((d >> 8) << 24) | ((d & 255u) << 16) | s;
                atomicAdd(&cnt[d >> 8], 1);
            } else ed[j] = 0xFFFFFFFFu;
        }
        __syncthreads();
        if (t < NBP) sbuf[t] = cnt[t];
        __syncthreads();
        for (int o = 1; o < NBP; o <<= 1) {
            int v = 0;
            if (t < NBP && t >= o) v = sbuf[t - o];
            __syncthreads();
            if (t < NBP) sbuf[t] += v;
            __syncthreads();
        }
        if (t < NBP) {
            loff[t] = sbuf[t] - cnt[t];
            lpos[t] = sbuf[t] - cnt[t];
            gbase[t] = (cnt[t] > 0) ? atomicAdd(&bucketCursor[t], cnt[t]) : 0;
        }
        __syncthreads();
#pragma unroll
        for (int j = 0; j < 8; ++j) {
            if (ed[j] != 0xFFFFFFFFu) {
                int b = ed[j] >> 24;
                int p = atomicAdd(&lpos[b], 1);
                stage[p] = ed[j];
            }
        }
        __syncthreads();
        for (int i = t; i < cntE; i += 512) {
            unsigned pr = stage[i];
            int b = pr >> 24;
            int pos = gbase[b] + (i - loff[b]);
            if (pos < CAP) edgeTmp[(size_t)b * CAP + pos] = pr;
        }
        return;
    }
    int wq = blockIdx.x - NB1;
    int l = wq / 449;
    int bx = wq - l * 449;
    if (bx < 320) {
        if (t < 192) {
            int k = bx, j = t;
            int third = j >> 6, c = j & 63;
            float out = 0.f;
            int r = -1;
            if (k < 64) r = (third == 0) ? k : -1;
            else        r = 64 + third * 256 + (k - 64);
            if (r >= 0) {
                const float* pw = post_w + (size_t)(l * 832 + r) * 64;
                const float* lw = lin_w + (size_t)l * 64 * 64;
                float s = 0.f;
                for (int kk = 0; kk < 64; ++kk) s += pw[kk] * lw[kk * 64 + c];
                out = s;
            }
            u16 h = f2bf(out);
            size_t o = ((size_t)l * 192 + j) * 320 + k;
            WT_hi[o] = h;
            WT_lo[o] = f2bf(out - bf2f(h));
        }
    } else if (bx < 448) {
        if (t < 64) {
            int c = bx - 320, k = t;
            float v = pre_w[(size_t)l * 8192 + (size_t)(k + (c >= 64 ? 64 : 0)) * 64 + (c & 63)];
            u16 h = f2bf(v);
            size_t o = ((size_t)l * 128 + c) * 64 + k;
            WpT_hi[o] = h;
            WpT_lo[o] = f2bf(v - bf2f(h));
        }
    } else {
        if (t < 64) {
            int c = t;
            const float* pb = post_b + l * 64;
            const float* lw = lin_w + (size_t)l * 64 * 64;
            float s = lin_b[l * 64 + c];
            for (int k = 0; k < 64; ++k) s += pb[k] * lw[k * 64 + c];
            bpp[l * 64 + c] = s;
        }
    }
}

// ---------------- pre2: counting-sort + layer-0 gemm1 (merged) ----------------
__global__ __launch_bounds__(512) void k_pre2(
    const unsigned* __restrict__ edgeTmp, const int* __restrict__ bucketCur,
    int* __restrict__ deg, int* __restrict__ offs, float* __restrict__ lsum,
    u16* __restrict__ srcSorted,
    const float* __restrict__ x, const u16* __restrict__ WpT_hi,
    const u16* __restrict__ WpT_lo, const float* __restrict__ pre_b,
    u16* __restrict__ Ph, u16* __restrict__ Qh,
    int N, int E, int NB) {
    __shared__ __align__(16) char smem[55296];
    int t = threadIdx.x;
    if ((int)blockIdx.x < NB) {
        int* scnt = (int*)smem;
        int* sbuf = (int*)(smem + 1024);
        int* lcur = (int*)(smem + 2048);
        int* lofs = (int*)(smem + 3072);
        float* fred = (float*)(smem + 4096);
        u16* stageSrc = (u16*)(smem + 5120);
        int* cntPs = (int*)(smem + 5120 + CAPS * 2);
        int b = blockIdx.x;
        int n0 = b << 8;
        int nodes = min(256, N - n0);
        if (t < NBP) { lcur[t] = 0; scnt[t] = 0; }
        __syncthreads();
        int cnt = min(bucketCur[b], CAP);
        const unsigned* ebase = edgeTmp + (size_t)b * CAP;
        for (int i = t; i < cnt; i += 512) atomicAdd(&lcur[(ebase[i] >> 16) & 255], 1);
        __syncthreads();
        float ls = 0.f;
        int d = 0, dP = 0;
        if (t < nodes) {
            d = lcur[t];
            deg[n0 + t] = d;
            ls = logf(fmaxf((float)d, 1.f) + 1.f);
            dP = (d + 3) & ~3;
        }
        if (t < 256) fred[t] = ls;
        if (t < NBP) sbuf[t] = dP;
        __syncthreads();
        for (int o = 1; o < NBP; o <<= 1) {
            int v = 0;
            if (t < NBP && t >= o) v = sbuf[t - o];
            __syncthreads();
            if (t < NBP) sbuf[t] += v;
            __syncthreads();
        }
        if (t < NBP) lofs[t] = sbuf[t] - dP;
        if (t < nodes) offs[n0 + t] = b * CAPS + (sbuf[t] - dP);
        if (t == NBP - 1) *cntPs = sbuf[t];
        __syncthreads();
        for (int o = 128; o > 0; o >>= 1) {
            if (t < o) fred[t] += fred[t + o];
            __syncthreads();
        }
        if (t == 0) atomicAdd(lsum, fred[0]);
        for (int i = t; i < cnt; i += 512) {
            unsigned p = ebase[i];
            int dl = (p >> 16) & 255;
            int r = atomicAdd(&scnt[dl], 1);
            stageSrc[lofs[dl] + r] = (u16)(p & 0xFFFFu);
        }
        __syncthreads();
        if (t < nodes && (d & 3)) {
            int lp = lofs[t];
            u16 lastv = stageSrc[lp + d - 1];
            for (int k = d; k < dP; ++k) stageSrc[lp + k] = lastv;
        }
        __syncthreads();
        int cntP = *cntPs;
        for (int i = t; i < cntP; i += 512) srcSorted[(size_t)b * CAPS + i] = stageSrc[i];
        return;
    }
    // ---- gemm1 body: 64 rows, threads 0..255, ONE hoisted barrier ----
    u16* Ah = (u16*)smem;            // 64*72 u16 = 9216 B
    u16* Al = (u16*)(smem + 9216);
    u16* Bh = (u16*)(smem + 18432);  // 128*72 u16 = 18432 B
    u16* Bl = (u16*)(smem + 36864);
    int rows0 = ((int)blockIdx.x - NB) * 64;
    int wid = t >> 6, lane = t & 63;
    int quad = lane >> 4, l16 = lane & 15;
    int wm = wid & 1, wn = wid >> 1;
    if (t < 256) {
#pragma unroll
        for (int it = 0; it < 2; ++it) {
            int task = it * 256 + t;
            int r = task >> 3, seg = task & 7;
            int row = rows0 + r;
            float4 v0 = make_float4(0.f, 0.f, 0.f, 0.f), v1 = v0;
            if (row < N) {
                v0 = *(const float4*)&x[(size_t)row * 64 + seg * 8];
                v1 = *(const float4*)&x[(size_t)row * 64 + seg * 8 + 4];
            }
            s16x8 hv, lv;
            split8(v0, v1, hv, lv);
            *(s16x8*)&Ah[r * 72 + seg * 8] = hv;
            *(s16x8*)&Al[r * 72 + seg * 8] = lv;
        }
#pragma unroll
        for (int it = 0; it < 4; ++it) {
            int task = it * 256 + t;
            int c = task >> 3, seg = task & 7;
            *(s16x8*)&Bh[c * 72 + seg * 8] = *(const s16x8*)&WpT_hi[(size_t)c * 64 + seg * 8];
            *(s16x8*)&Bl[c * 72 + seg * 8] = *(const s16x8*)&WpT_lo[(size_t)c * 64 + seg * 8];
        }
    }
    __syncthreads();
    if (t < 256) {
        f32x4 acc[2][4];
#pragma unroll
        for (int mt = 0; mt < 2; ++mt)
#pragma unroll
            for (int tt = 0; tt < 4; ++tt) acc[mt][tt] = (f32x4){0.f, 0.f, 0.f, 0.f};
#pragma unroll
        for (int c = 0; c < 2; ++c) {
            s16x8 ah[2], al[2];
#pragma unroll
            for (int mt = 0; mt < 2; ++mt) {
                int r = wm * 32 + mt * 16 + l16;
                ah[mt] = *(s16x8*)&Ah[r * 72 + c * 32 + quad * 8];
                al[mt] = *(s16x8*)&Al[r * 72 + c * 32 + quad * 8];
            }
#pragma unroll
            for (int tt = 0; tt < 4; ++tt) {
                int cc = wn * 64 + tt * 16 + l16;
                s16x8 bh = *(s16x8*)&Bh[cc * 72 + c * 32 + quad * 8];
                s16x8 bl = *(s16x8*)&Bl[cc * 72 + c * 32 + quad * 8];
#pragma unroll
                for (int mt = 0; mt < 2; ++mt) {
                    acc[mt][tt] = MFMA(ah[mt], bh, acc[mt][tt]);
                    acc[mt][tt] = MFMA(ah[mt], bl, acc[mt][tt]);
                    if (wn == 0) acc[mt][tt] = MFMA(al[mt], bh, acc[mt][tt]);
                }
            }
        }
#pragma unroll
        for (int mt = 0; mt < 2; ++mt)
#pragma unroll
            for (int tt = 0; tt < 4; ++tt) {
                int col = wn * 64 + tt * 16 + l16;
#pragma unroll
                for (int r = 0; r < 4; ++r) {
                    int row = rows0 + wm * 32 + mt * 16 + quad * 4 + r;
                    if (row >= N) continue;
                    float v = acc[mt][tt][r];
                    if (col < 64) Ph[(size_t)row * 64 + col] = f2bf(v + pre_b[col]);
                    else          Qh[(size_t)row * 64 + (col - 64)] = f2bf(v);
                }
            }
    }
}

// ---------------- per-layer kernels ----------------

// aggregation v4 (round-3 proven): one wave = 4 nodes; padded CSR, branch-free body.
__global__ __launch_bounds__(256) void k_agg(const u16* __restrict__ Ph,
                                             const u16* __restrict__ Qh,
                                             const int* __restrict__ offs,
                                             const int* __restrict__ degp,
                                             const u16* __restrict__ ss,
                                             u16* __restrict__ AGGh, int N) {
    int w = threadIdx.x >> 6, lane = threadIdx.x & 63;
    int g = lane >> 4;              // node sub-slot 0..3
    int f4b = (lane & 15) << 3;     // byte offset of this lane's 4 features
    int node = blockIdx.x * 16 + w * 4 + g;
    int nc = min(node, N - 1);
    int beg = offs[nc];
    int d = (node < N) ? degp[nc] : 0;
    int dP = (d + 3) & ~3;
    int end = beg + dP;
    int mdP = dP;
    mdP = max(mdP, __shfl_xor(mdP, 16));
    mdP = max(mdP, __shfl_xor(mdP, 32));
    int trips = mdP >> 2;

    float sum0 = 0.f, sum1 = 0.f, sum2 = 0.f, sum3 = 0.f;
    float sq0 = 0.f, sq1 = 0.f, sq2 = 0.f, sq3 = 0.f;
    float mx0 = -3.4e38f, mx1 = -3.4e38f, mx2 = -3.4e38f, mx3 = -3.4e38f;
    float mn0 = 3.4e38f, mn1 = 3.4e38f, mn2 = 3.4e38f, mn3 = 3.4e38f;

    const char* qbase = (const char*)Qh;

#define ACC4(LO, HI)                                                        \
    {                                                                       \
        float q0 = __uint_as_float((LO) << 16);                             \
        float q1 = __uint_as_float((LO) & 0xFFFF0000u);                     \
        float q2 = __uint_as_float((HI) << 16);                             \
        float q3 = __uint_as_float((HI) & 0xFFFF0000u);                     \
        sum0 += q0; sq0 = fmaf(q0, q0, sq0);                                \
        mx0 = fmaxf(mx0, q0); mn0 = fminf(mn0, q0);                         \
        sum1 += q1; sq1 = fmaf(q1, q1, sq1);                                \
        mx1 = fmaxf(mx1, q1); mn1 = fminf(mn1, q1);                         \
        sum2 += q2; sq2 = fmaf(q2, q2, sq2);                                \
        mx2 = fmaxf(mx2, q2); mn2 = fminf(mn2, q2);                         \
        sum3 += q3; sq3 = fmaf(q3, q3, sq3);                                \
        mx3 = fmaxf(mx3, q3); mn3 = fminf(mn3, q3);                         \
    }

    int e = beg;
    for (int it = 0; it < trips; ++it, e += 4) {
        if (e < end) {
            uint2 sw = *(const uint2*)(ss + e);  // 4 packed src ids
            unsigned a0 = ((sw.x & 0xFFFFu) << 7) | (unsigned)f4b;
            unsigned a1 = ((sw.x >> 16) << 7) | (unsigned)f4b;
            unsigned a2 = ((sw.y & 0xFFFFu) << 7) | (unsigned)f4b;
            unsigned a3 = ((sw.y >> 16) << 7) | (unsigned)f4b;
            uint2 qa = *(const uint2*)(qbase + a0);
            uint2 qb = *(const uint2*)(qbase + a1);
            uint2 qc = *(const uint2*)(qbase + a2);
            uint2 qd = *(const uint2*)(qbase + a3);
            ACC4(qa.x, qa.y);
            ACC4(qb.x, qb.y);
            ACC4(qc.x, qc.y);
            ACC4(qd.x, qd.y);
        }
    }
#undef ACC4

    if (d & 3) {
        unsigned sl = ss[beg + d - 1];
        uint2 ql = *(const uint2*)(qbase + ((sl << 7) | (unsigned)f4b));
        float padf = (float)(dP - d);
        float qL0 = __uint_as_float(ql.x << 16);
        float qL1 = __uint_as_float(ql.x & 0xFFFF0000u);
        float qL2 = __uint_as_float(ql.y << 16);
        float qL3 = __uint_as_float(ql.y & 0xFFFF0000u);
        float t0 = padf * qL0, t1 = padf * qL1, t2 = padf * qL2, t3 = padf * qL3;
        sum0 -= t0; sq0 = fmaf(-t0, qL0, sq0);
        sum1 -= t1; sq1 = fmaf(-t1, qL1, sq1);
        sum2 -= t2; sq2 = fmaf(-t2, qL2, sq2);
        sum3 -= t3; sq3 = fmaf(-t3, qL3, sq3);
    }

    float dc = fmaxf((float)d, 1.f);
    float inv = 1.0f / dc;
    float e0 = sum0 * inv, e1 = sum1 * inv, e2 = sum2 * inv, e3 = sum3 * inv;
    float sd0 = sqrtf(fmaxf(fmaf(-e0, e0, sq0 * inv), 0.f) + EPSV);
    float sd1 = sqrtf(fmaxf(fmaf(-e1, e1, sq1 * inv), 0.f) + EPSV);
    float sd2 = sqrtf(fmaxf(fmaf(-e2, e2, sq2 * inv), 0.f) + EPSV);
    float sd3 = sqrtf(fmaxf(fmaf(-e3, e3, sq3 * inv), 0.f) + EPSV);

    uint2 pw = *(const uint2*)((const char*)Ph + (((unsigned)nc << 7) | (unsigned)f4b));
    float p0 = __uint_as_float(pw.x << 16), p1 = __uint_as_float(pw.x & 0xFFFF0000u);
    float p2 = __uint_as_float(pw.y << 16), p3 = __uint_as_float(pw.y & 0xFFFF0000u);

    bool he = d > 0;
    float m0 = he ? p0 + e0 : 0.f, m1 = he ? p1 + e1 : 0.f;
    float m2 = he ? p2 + e2 : 0.f, m3 = he ? p3 + e3 : 0.f;
    float X0 = he ? p0 + mx0 : 0.f, X1 = he ? p1 + mx1 : 0.f;
    float X2 = he ? p2 + mx2 : 0.f, X3 = he ? p3 + mx3 : 0.f;
    float n0 = he ? p0 + mn0 : 0.f, n1 = he ? p1 + mn1 : 0.f;
    float n2 = he ? p2 + mn2 : 0.f, n3 = he ? p3 + mn3 : 0.f;

    if (node < N) {
        u16* out = (u16*)((char*)AGGh + (((unsigned)node << 9) | (unsigned)f4b));
        *(u16x4*)(out)       = (u16x4){f2bf(m0), f2bf(m1), f2bf(m2), f2bf(m3)};
        *(u16x4*)(out + 64)  = (u16x4){f2bf(X0), f2bf(X1), f2bf(X2), f2bf(X3)};
        *(u16x4*)(out + 128) = (u16x4){f2bf(n0), f2bf(n1), f2bf(n2), f2bf(n3)};
        *(u16x4*)(out + 192) = (u16x4){f2bf(sd0), f2bf(sd1), f2bf(sd2), f2bf(sd3)};
    }
}

// gemm2 v6: r5's proven 2-barrier LDS schedule with K-CHUNK=64 -> barrier-drain
// count halved (~11 vs ~25 per block). Each 64-k chunk computed as two 32-k
// halves in r5's exact order (bit-identical MFMA sequence & operands).
// LDS 73.7KB phase-union (gfx950 allows >64KB/workgroup): pitch 72 = 64+8 pad.
__global__ __launch_bounds__(512) void k_gemm2(const float* __restrict__ hIn,
                                               const u16* __restrict__ AGGh,
                                               const u16* __restrict__ WT_hi,
                                               const u16* __restrict__ WT_lo,
                                               const float* __restrict__ bpp,
                                               const int* __restrict__ degp,
                                               const float* __restrict__ lsum,
                                               float* __restrict__ hOut,
                                               int doNext,
                                               const u16* __restrict__ WpN_hi,
                                               const u16* __restrict__ WpN_lo,
                                               const float* __restrict__ pre_bN,
                                               u16* __restrict__ PhN,
                                               u16* __restrict__ QhN, int M) {
    __shared__ __align__(16) char smem[73728];
    u16* Ah  = (u16*)smem;             // 128x72 A-hi (all phases)
    u16* Al  = (u16*)(smem + 18432);   // 128x72 A-lo (phase1, phaseC)
    u16* B1h = (u16*)(smem + 36864);   // 64x72  (phase1)
    u16* B1l = (u16*)(smem + 55296);   // 64x72  (phase1)
    u16* B2h = (u16*)(smem + 18432);   // 192x72 (phase2)
    u16* B2l = (u16*)(smem + 46080);   // 192x72 (phase2)
    u16* BCh = (u16*)(smem + 36864);   // 128x72 (phaseC)
    u16* BCl = (u16*)(smem + 55296);   // 128x72 (phaseC)
    int t = threadIdx.x, wid = t >> 6, lane = t & 63;
    int rows0 = blockIdx.x * 128;
    int quad = lane >> 4, l16 = lane & 15;
    int wm = wid & 3, wn = wid >> 2;

    f32x4 acc[2][6];  // [mt][cg + third*2]
#pragma unroll
    for (int mt = 0; mt < 2; ++mt)
#pragma unroll
        for (int tt = 0; tt < 6; ++tt) acc[mt][tt] = (f32x4){0.f, 0.f, 0.f, 0.f};

    // ---- Phase 1: k 0..63 over hIn (hi/lo split), cols 0:64 — ONE staged chunk ----
#pragma unroll
    for (int it = 0; it < 2; ++it) {  // A: 128 rows x 8 segs = 1024 tasks
        int task = it * 512 + t;
        int r = task >> 3, seg = task & 7;
        int row = rows0 + r;
        float4 v0 = make_float4(0.f, 0.f, 0.f, 0.f), v1 = v0;
        if (row < M) {
            v0 = *(const float4*)&hIn[(size_t)row * 64 + seg * 8];
            v1 = *(const float4*)&hIn[(size_t)row * 64 + seg * 8 + 4];
        }
        s16x8 hv, lv;
        split8(v0, v1, hv, lv);
        *(s16x8*)&Ah[r * 72 + seg * 8] = hv;
        *(s16x8*)&Al[r * 72 + seg * 8] = lv;
    }
    {  // B: 64 cols x 8 segs = 512 tasks
        int c = t >> 3, seg = t & 7;
        *(s16x8*)&B1h[c * 72 + seg * 8] = *(const s16x8*)&WT_hi[(size_t)c * 320 + seg * 8];
        *(s16x8*)&B1l[c * 72 + seg * 8] = *(const s16x8*)&WT_lo[(size_t)c * 320 + seg * 8];
    }
    __syncthreads();
#pragma unroll
    for (int half = 0; half < 2; ++half) {
        s16x8 ah[2], al[2];
#pragma unroll
        for (int mt = 0; mt < 2; ++mt) {
            int r = wm * 32 + mt * 16 + l16;
            ah[mt] = *(s16x8*)&Ah[r * 72 + half * 32 + quad * 8];
            al[mt] = *(s16x8*)&Al[r * 72 + half * 32 + quad * 8];
        }
#pragma unroll
        for (int cg = 0; cg < 2; ++cg) {
            int cc = wn * 32 + cg * 16 + l16;
            s16x8 bh = *(s16x8*)&B1h[cc * 72 + half * 32 + quad * 8];
            s16x8 bl = *(s16x8*)&B1l[cc * 72 + half * 32 + quad * 8];
#pragma unroll
            for (int mt = 0; mt < 2; ++mt) {
                acc[mt][cg] = MFMA(ah[mt], bh, acc[mt][cg]);
                acc[mt][cg] = MFMA(al[mt], bh, acc[mt][cg]);
                acc[mt][cg] = MFMA(ah[mt], bl, acc[mt][cg]);
            }
        }
    }

    // ---- Phase 2: k 64..319 over AGGh, 4 chunks of 64-k, all 192 cols ----
    for (int chunk = 0; chunk < 4; ++chunk) {
        int k0g = 64 + chunk * 64;
        __syncthreads();  // previous chunk's (or phase1's) LDS reads complete
#pragma unroll
        for (int it = 0; it < 2; ++it) {  // A: 1024 tasks
            int task = it * 512 + t;
            int r = task >> 3, seg = task & 7;
            int row = rows0 + r;
            s16x8 v = (s16x8){0, 0, 0, 0, 0, 0, 0, 0};
            if (row < M) v = *(const s16x8*)&AGGh[(size_t)row * 256 + chunk * 64 + seg * 8];
            *(s16x8*)&Ah[r * 72 + seg * 8] = v;
        }
#pragma unroll
        for (int it = 0; it < 3; ++it) {  // B: 192 cols x 8 segs = 1536 tasks (hi+lo)
            int task = it * 512 + t;
            int c = task >> 3, seg = task & 7;
            *(s16x8*)&B2h[c * 72 + seg * 8] = *(const s16x8*)&WT_hi[(size_t)c * 320 + k0g + seg * 8];
            *(s16x8*)&B2l[c * 72 + seg * 8] = *(const s16x8*)&WT_lo[(size_t)c * 320 + k0g + seg * 8];
        }
        __syncthreads();
#pragma unroll
        for (int half = 0; half < 2; ++half) {
            s16x8 ah[2];
#pragma unroll
            for (int mt = 0; mt < 2; ++mt) {
                int r = wm * 32 + mt * 16 + l16;
                ah[mt] = *(s16x8*)&Ah[r * 72 + half * 32 + quad * 8];
            }
#pragma unroll
            for (int tt = 0; tt < 6; ++tt) {
                int cc = wn * 32 + (tt & 1) * 16 + (tt >> 1) * 64 + l16;
                s16x8 bh = *(s16x8*)&B2h[cc * 72 + half * 32 + quad * 8];
                s16x8 bl = *(s16x8*)&B2l[cc * 72 + half * 32 + quad * 8];
#pragma unroll
                for (int mt = 0; mt < 2; ++mt) {
                    acc[mt][tt] = MFMA(ah[mt], bh, acc[mt][tt]);
                    acc[mt][tt] = MFMA(ah[mt], bl, acc[mt][tt]);
                }
            }
        }
    }

    // ---- Epilogue: combine thirds (amp/att inline), residual + bias ----
    float hv[2][2][4];
    float avg = *lsum / (float)M;
#pragma unroll
    for (int mt = 0; mt < 2; ++mt)
#pragma unroll
        for (int r = 0; r < 4; ++r) {
            int row = rows0 + wm * 32 + mt * 16 + quad * 4 + r;
            float am = 1.f, at = 1.f, hin0 = 0.f, hin1 = 0.f;
            if (row < M) {
                float dc = fmaxf((float)degp[row], 1.f);
                float ld = logf(dc + 1.f);
                am = ld / avg;
                at = avg / ld;
                hin0 = hIn[(size_t)row * 64 + wn * 32 + l16];
                hin1 = hIn[(size_t)row * 64 + wn * 32 + 16 + l16];
            }
#pragma unroll
            for (int cg = 0; cg < 2; ++cg) {
                int col = wn * 32 + cg * 16 + l16;
                float v = acc[mt][cg][r] + am * acc[mt][cg + 2][r] + at * acc[mt][cg + 4][r]
                        + (cg == 0 ? hin0 : hin1) + bpp[col];
                hv[mt][cg][r] = v;
                if (row < M) hOut[(size_t)row * 64 + col] = v;
            }
        }

    // ---- Phase C (doNext): gemm1(l+1) from in-register h' — ONE staged chunk ----
    if (doNext) {
        __syncthreads();  // all phase-2 LDS reads complete before overwrite
#pragma unroll
        for (int it = 0; it < 2; ++it) {  // WpN: 128 cols x 8 segs = 1024 tasks
            int task = it * 512 + t;
            int c = task >> 3, seg = task & 7;
            *(s16x8*)&BCh[c * 72 + seg * 8] = *(const s16x8*)&WpN_hi[(size_t)c * 64 + seg * 8];
            *(s16x8*)&BCl[c * 72 + seg * 8] = *(const s16x8*)&WpN_lo[(size_t)c * 64 + seg * 8];
        }
        // stage h' (each thread writes its own 16 elements; all 128x64 covered)
#pragma unroll
        for (int mt = 0; mt < 2; ++mt)
#pragma unroll
            for (int cg = 0; cg < 2; ++cg) {
                int lc = wn * 32 + cg * 16 + l16;  // k-index 0..63
#pragma unroll
                for (int r = 0; r < 4; ++r) {
                    int rl = wm * 32 + mt * 16 + quad * 4 + r;
                    float v = hv[mt][cg][r];
                    u16 hi = f2bf(v);
                    Ah[rl * 72 + lc] = hi;
                    Al[rl * 72 + lc] = f2bf(v - bf2f(hi));
                }
            }
        __syncthreads();

        f32x4 acc2[2][4];
#pragma unroll
        for (int mt = 0; mt < 2; ++mt)
#pragma unroll
            for (int tt = 0; tt < 4; ++tt) acc2[mt][tt] = (f32x4){0.f, 0.f, 0.f, 0.f};

#pragma unroll
        for (int half = 0; half < 2; ++half) {
            s16x8 ah[2], al[2];
#pragma unroll
            for (int mt = 0; mt < 2; ++mt) {
                int r = wm * 32 + mt * 16 + l16;
                ah[mt] = *(s16x8*)&Ah[r * 72 + half * 32 + quad * 8];
                al[mt] = *(s16x8*)&Al[r * 72 + half * 32 + quad * 8];
            }
#pragma unroll
            for (int tt = 0; tt < 4; ++tt) {
                int cc = wn * 64 + tt * 16 + l16;
                s16x8 bh = *(s16x8*)&BCh[cc * 72 + half * 32 + quad * 8];
                s16x8 bl = *(s16x8*)&BCl[cc * 72 + half * 32 + quad * 8];
#pragma unroll
                for (int mt = 0; mt < 2; ++mt) {
                    acc2[mt][tt] = MFMA(ah[mt], bh, acc2[mt][tt]);
                    acc2[mt][tt] = MFMA(ah[mt], bl, acc2[mt][tt]);
                    if (wn == 0) acc2[mt][tt] = MFMA(al[mt], bh, acc2[mt][tt]);
                }
            }
        }

#pragma unroll
        for (int mt = 0; mt < 2; ++mt)
#pragma unroll
            for (int tt = 0; tt < 4; ++tt) {
                int col = wn * 64 + tt * 16 + l16;
#pragma unroll
                for (int r = 0; r < 4; ++r) {
                    int row = rows0 + wm * 32 + mt * 16 + quad * 4 + r;
                    if (row >= M) continue;
                    float v = acc2[mt][tt][r];
                    if (col < 64) PhN[(size_t)row * 64 + col] = f2bf(v + pre_bN[col]);
                    else          QhN[(size_t)row * 64 + (col - 64)] = f2bf(v);
                }
            }
    }
}

// ---------------- launch ----------------

extern "C" void kernel_launch(void* const* d_in, const int* in_sizes, int n_in,
                              void* d_out, int out_size, void* d_ws, size_t ws_size,
                              hipStream_t stream) {
    const float* x      = (const float*)d_in[0];
    const int*   ei     = (const int*)d_in[1];
    const float* pre_w  = (const float*)d_in[2];
    const float* pre_b  = (const float*)d_in[3];
    const float* post_w = (const float*)d_in[4];
    const float* post_b = (const float*)d_in[5];
    const float* lin_w  = (const float*)d_in[6];
    const float* lin_b  = (const float*)d_in[7];

    const int N = in_sizes[0] / 64;
    const int E = in_sizes[1] / 2;
    const int L = in_sizes[2] / (128 * 64);

    const int* srcIdx = ei;
    const int* dstIdx = ei + E;

    char* ws = (char*)d_ws;
    size_t off = 0;
    auto alloc = [&](size_t bytes) {
        void* p = ws + off;
        off += (bytes + 255) & ~(size_t)255;
        return p;
    };
    int*      deg        = (int*)alloc((size_t)N * 4);
    int*      offs       = (int*)alloc((size_t)(N + 1) * 4);
    u16*      srcSorted  = (u16*)alloc((size_t)NBP * CAPS * 2);
    unsigned* edgeTmp    = (unsigned*)alloc((size_t)NBP * CAP * 4);
    int*      bucketCur  = (int*)alloc(NBP * 4);
    float*    lsum       = (float*)alloc(256);
    u16*      WpT_hi     = (u16*)alloc((size_t)L * 128 * 64 * 2);
    u16*      WpT_lo     = (u16*)alloc((size_t)L * 128 * 64 * 2);
    u16*      WT_hi      = (u16*)alloc((size_t)L * 192 * 320 * 2);
    u16*      WT_lo      = (u16*)alloc((size_t)L * 192 * 320 * 2);
    float*    bpp        = (float*)alloc((size_t)L * 64 * 4);
    u16*      Ph         = (u16*)alloc((size_t)N * 64 * 2);
    u16*      Qh         = (u16*)alloc((size_t)N * 64 * 2);
    u16*      AGGh       = (u16*)alloc((size_t)N * 256 * 2);
    float*    hA         = (float*)alloc((size_t)N * 64 * 4);
    float*    hB         = (float*)alloc((size_t)N * 64 * 4);
    (void)ws_size;

    int NB = (N + 255) >> 8;
    int NB1 = (E + EPB3 - 1) / EPB3;
    int gblk = (N + 63) / 64;
    int gblk2 = (N + 127) / 128;

    hipMemsetAsync(bucketCur, 0, NBP * 4, stream);
    hipMemsetAsync(lsum, 0, 4, stream);

    k_pre1<<<NB1 + 449 * L, 512, 0, stream>>>(
        srcIdx, dstIdx, E, bucketCur, edgeTmp,
        pre_w, post_w, post_b, lin_w, lin_b,
        WpT_hi, WpT_lo, WT_hi, WT_lo, bpp, NB1);

    k_pre2<<<NB + gblk, 512, 0, stream>>>(
        edgeTmp, bucketCur, deg, offs, lsum, srcSorted,
        x, WpT_hi, WpT_lo, pre_b, Ph, Qh, N, E, NB);

    const float* hIn = x;
    float* hbuf[2] = {hA, hB};
    for (int l = 0; l < L; ++l) {
        float* hOut = (l == L - 1) ? (float*)d_out : hbuf[l & 1];
        int dn = (l < L - 1) ? 1 : 0;
        int ln = dn ? (l + 1) : 0;
        k_agg<<<(N + 15) / 16, 256, 0, stream>>>(Ph, Qh, offs, deg, srcSorted, AGGh, N);
        k_gemm2<<<gblk2, 512, 0, stream>>>(hIn, AGGh,
                                           WT_hi + (size_t)l * 192 * 320,
                                           WT_lo + (size_t)l * 192 * 320,
                                           bpp + (size_t)l * 64,
                                           deg, lsum, hOut, dn,
                                           WpT_hi + (size_t)ln * 128 * 64,
                                           WpT_lo + (size_t)ln * 128 * 64,
                                           pre_b + (size_t)ln * 64,
                                           Ph, Qh, N);
        hIn = hOut;
    }
}

// Round 12
// 253.237 us; speedup vs baseline: 1.2305x; 1.2305x over previous
//
#include <hip/hip_runtime.h>
#include <math.h>

#define EPSV 1e-5f
#define EPB3 4096  // edges per bucket-pass block (196 blocks, proven config)
#define NBP 256    // buckets of 256 nodes (N <= 65536; src packed in 16 bits)
#define CAP 6144   // per-bucket edgeTmp slab capacity (mean ~4081, +32 sigma)
#define CAPS (CAP + 768)  // padded sorted-slab capacity (pad <=3 per node)

typedef short s16x8 __attribute__((ext_vector_type(8)));
typedef float f32x4 __attribute__((ext_vector_type(4)));
typedef unsigned short u16;
typedef unsigned short u16x4 __attribute__((ext_vector_type(4)));

#define MFMA(a, b, c) __builtin_amdgcn_mfma_f32_16x16x32_bf16(a, b, c, 0, 0, 0)

__device__ inline u16 f2bf(float f) {
    unsigned u = __float_as_uint(f);
    return (u16)((u + 0x7FFF + ((u >> 16) & 1)) >> 16);
}
__device__ inline float bf2f(u16 h) { return __uint_as_float(((unsigned)h) << 16); }

__device__ inline void split8(const float4& a, const float4& b, s16x8& hv, s16x8& lv) {
    float f[8] = {a.x, a.y, a.z, a.w, b.x, b.y, b.z, b.w};
#pragma unroll
    for (int i = 0; i < 8; ++i) {
        u16 h = f2bf(f[i]);
        hv[i] = (short)h;
        lv[i] = (short)f2bf(f[i] - bf2f(h));
    }
}

// async global->LDS, 16B per lane; LDS dest = wave-uniform base + lane*16.
typedef const __attribute__((address_space(1))) unsigned int* gp_t;
typedef __attribute__((address_space(3))) unsigned int* lp_t;
__device__ inline void gll(const void* g, void* l) {
    __builtin_amdgcn_global_load_lds((gp_t)g, (lp_t)l, 16, 0, 0);
}

// swizzled u16 index within a pitch-64 tile: row r, 16B-chunk s (0..7)
__device__ inline int swzi(int r, int s) { return r * 64 + ((s ^ (r & 7)) << 3); }

// ---------------- pre1: bucket partition + weight prep (merged) ----------------
__global__ __launch_bounds__(512) void k_pre1(
    const int* __restrict__ src, const int* __restrict__ dst, int E,
    int* __restrict__ bucketCursor, unsigned* __restrict__ edgeTmp,
    const float* __restrict__ pre_w, const float* __restrict__ post_w,
    const float* __restrict__ post_b, const float* __restrict__ lin_w,
    const float* __restrict__ lin_b, u16* __restrict__ WpT_hi,
    u16* __restrict__ WpT_lo, u16* __restrict__ WT_hi, u16* __restrict__ WT_lo,
    float* __restrict__ bpp, int NB1) {
    __shared__ int cnt[NBP], loff[NBP], lpos[NBP], gbase[NBP], sbuf[NBP];
    __shared__ unsigned stage[EPB3];
    int t = threadIdx.x;
    if ((int)blockIdx.x < NB1) {
        int base = blockIdx.x * EPB3;
        int cntE = min(EPB3, E - base);
        if (t < NBP) cnt[t] = 0;
        __syncthreads();
        unsigned ed[8];
#pragma unroll
        for (int j = 0; j < 8; ++j) {
            int idx = j * 512 + t;
            if (idx < cntE) {
                int e = base + idx;
                unsigned s = (unsigned)src[e];
                unsigned d = (unsigned)dst[e];
                ed[j] = ((d >> 8) << 24) | ((d & 255u) << 16) | s;
                atomicAdd(&cnt[d >> 8], 1);
            } else ed[j] = 0xFFFFFFFFu;
        }
        __syncthreads();
        if (t < NBP) sbuf[t] = cnt[t];
        __syncthreads();
        for (int o = 1; o < NBP; o <<= 1) {
            int v = 0;
            if (t < NBP && t >= o) v = sbuf[t - o];
            __syncthreads();
            if (t < NBP) sbuf[t] += v;
            __syncthreads();
        }
        if (t < NBP) {
            loff[t] = sbuf[t] - cnt[t];
            lpos[t] = sbuf[t] - cnt[t];
            gbase[t] = (cnt[t] > 0) ? atomicAdd(&bucketCursor[t], cnt[t]) : 0;
        }
        __syncthreads();
#pragma unroll
        for (int j = 0; j < 8; ++j) {
            if (ed[j] != 0xFFFFFFFFu) {
                int b = ed[j] >> 24;
                int p = atomicAdd(&lpos[b], 1);
                stage[p] = ed[j];
            }
        }
        __syncthreads();
        for (int i = t; i < cntE; i += 512) {
            unsigned pr = stage[i];
            int b = pr >> 24;
            int pos = gbase[b] + (i - loff[b]);
            if (pos < CAP) edgeTmp[(size_t)b * CAP + pos] = pr;
        }
        return;
    }
    int wq = blockIdx.x - NB1;
    int l = wq / 449;
    int bx = wq - l * 449;
    if (bx < 320) {
        if (t < 192) {
            int k = bx, j = t;
            int third = j >> 6, c = j & 63;
            float out = 0.f;
            int r = -1;
            if (k < 64) r = (third == 0) ? k : -1;
            else        r = 64 + third * 256 + (k - 64);
            if (r >= 0) {
                const float* pw = post_w + (size_t)(l * 832 + r) * 64;
                const float* lw = lin_w + (size_t)l * 64 * 64;
                float s = 0.f;
                for (int kk = 0; kk < 64; ++kk) s += pw[kk] * lw[kk * 64 + c];
                out = s;
            }
            u16 h = f2bf(out);
            size_t o = ((size_t)l * 192 + j) * 320 + k;
            WT_hi[o] = h;
            WT_lo[o] = f2bf(out - bf2f(h));
        }
    } else if (bx < 448) {
        if (t < 64) {
            int c = bx - 320, k = t;
            float v = pre_w[(size_t)l * 8192 + (size_t)(k + (c >= 64 ? 64 : 0)) * 64 + (c & 63)];
            u16 h = f2bf(v);
            size_t o = ((size_t)l * 128 + c) * 64 + k;
            WpT_hi[o] = h;
            WpT_lo[o] = f2bf(v - bf2f(h));
        }
    } else {
        if (t < 64) {
            int c = t;
            const float* pb = post_b + l * 64;
            const float* lw = lin_w + (size_t)l * 64 * 64;
            float s = lin_b[l * 64 + c];
            for (int k = 0; k < 64; ++k) s += pb[k] * lw[k * 64 + c];
            bpp[l * 64 + c] = s;
        }
    }
}

// ---------------- pre2: counting-sort + layer-0 gemm1 (merged) ----------------
__global__ __launch_bounds__(512) void k_pre2(
    const unsigned* __restrict__ edgeTmp, const int* __restrict__ bucketCur,
    int* __restrict__ deg, int* __restrict__ offs, float* __restrict__ lsum,
    u16* __restrict__ srcSorted,
    const float* __restrict__ x, const u16* __restrict__ WpT_hi,
    const u16* __restrict__ WpT_lo, const float* __restrict__ pre_b,
    u16* __restrict__ Ph, u16* __restrict__ Qh,
    int N, int E, int NB) {
    __shared__ __align__(16) char smem[55296];
    int t = threadIdx.x;
    if ((int)blockIdx.x < NB) {
        int* scnt = (int*)smem;
        int* sbuf = (int*)(smem + 1024);
        int* lcur = (int*)(smem + 2048);
        int* lofs = (int*)(smem + 3072);
        float* fred = (float*)(smem + 4096);
        u16* stageSrc = (u16*)(smem + 5120);
        int* cntPs = (int*)(smem + 5120 + CAPS * 2);
        int b = blockIdx.x;
        int n0 = b << 8;
        int nodes = min(256, N - n0);
        if (t < NBP) { lcur[t] = 0; scnt[t] = 0; }
        __syncthreads();
        int cnt = min(bucketCur[b], CAP);
        const unsigned* ebase = edgeTmp + (size_t)b * CAP;
        for (int i = t; i < cnt; i += 512) atomicAdd(&lcur[(ebase[i] >> 16) & 255], 1);
        __syncthreads();
        float ls = 0.f;
        int d = 0, dP = 0;
        if (t < nodes) {
            d = lcur[t];
            deg[n0 + t] = d;
            ls = logf(fmaxf((float)d, 1.f) + 1.f);
            dP = (d + 3) & ~3;
        }
        if (t < 256) fred[t] = ls;
        if (t < NBP) sbuf[t] = dP;
        __syncthreads();
        for (int o = 1; o < NBP; o <<= 1) {
            int v = 0;
            if (t < NBP && t >= o) v = sbuf[t - o];
            __syncthreads();
            if (t < NBP) sbuf[t] += v;
            __syncthreads();
        }
        if (t < NBP) lofs[t] = sbuf[t] - dP;
        if (t < nodes) offs[n0 + t] = b * CAPS + (sbuf[t] - dP);
        if (t == NBP - 1) *cntPs = sbuf[t];
        __syncthreads();
        for (int o = 128; o > 0; o >>= 1) {
            if (t < o) fred[t] += fred[t + o];
            __syncthreads();
        }
        if (t == 0) atomicAdd(lsum, fred[0]);
        for (int i = t; i < cnt; i += 512) {
            unsigned p = ebase[i];
            int dl = (p >> 16) & 255;
            int r = atomicAdd(&scnt[dl], 1);
            stageSrc[lofs[dl] + r] = (u16)(p & 0xFFFFu);
        }
        __syncthreads();
        if (t < nodes && (d & 3)) {
            int lp = lofs[t];
            u16 lastv = stageSrc[lp + d - 1];
            for (int k = d; k < dP; ++k) stageSrc[lp + k] = lastv;
        }
        __syncthreads();
        int cntP = *cntPs;
        for (int i = t; i < cntP; i += 512) srcSorted[(size_t)b * CAPS + i] = stageSrc[i];
        return;
    }
    // ---- gemm1 body: 64 rows, threads 0..255, ONE hoisted barrier ----
    u16* Ah = (u16*)smem;            // 64*72 u16 = 9216 B
    u16* Al = (u16*)(smem + 9216);
    u16* Bh = (u16*)(smem + 18432);  // 128*72 u16 = 18432 B
    u16* Bl = (u16*)(smem + 36864);
    int rows0 = ((int)blockIdx.x - NB) * 64;
    int wid = t >> 6, lane = t & 63;
    int quad = lane >> 4, l16 = lane & 15;
    int wm = wid & 1, wn = wid >> 1;
    if (t < 256) {
#pragma unroll
        for (int it = 0; it < 2; ++it) {
            int task = it * 256 + t;
            int r = task >> 3, seg = task & 7;
            int row = rows0 + r;
            float4 v0 = make_float4(0.f, 0.f, 0.f, 0.f), v1 = v0;
            if (row < N) {
                v0 = *(const float4*)&x[(size_t)row * 64 + seg * 8];
                v1 = *(const float4*)&x[(size_t)row * 64 + seg * 8 + 4];
            }
            s16x8 hv, lv;
            split8(v0, v1, hv, lv);
            *(s16x8*)&Ah[r * 72 + seg * 8] = hv;
            *(s16x8*)&Al[r * 72 + seg * 8] = lv;
        }
#pragma unroll
        for (int it = 0; it < 4; ++it) {
            int task = it * 256 + t;
            int c = task >> 3, seg = task & 7;
            *(s16x8*)&Bh[c * 72 + seg * 8] = *(const s16x8*)&WpT_hi[(size_t)c * 64 + seg * 8];
            *(s16x8*)&Bl[c * 72 + seg * 8] = *(const s16x8*)&WpT_lo[(size_t)c * 64 + seg * 8];
        }
    }
    __syncthreads();
    if (t < 256) {
        f32x4 acc[2][4];
#pragma unroll
        for (int mt = 0; mt < 2; ++mt)
#pragma unroll
            for (int tt = 0; tt < 4; ++tt) acc[mt][tt] = (f32x4){0.f, 0.f, 0.f, 0.f};
#pragma unroll
        for (int c = 0; c < 2; ++c) {
            s16x8 ah[2], al[2];
#pragma unroll
            for (int mt = 0; mt < 2; ++mt) {
                int r = wm * 32 + mt * 16 + l16;
                ah[mt] = *(s16x8*)&Ah[r * 72 + c * 32 + quad * 8];
                al[mt] = *(s16x8*)&Al[r * 72 + c * 32 + quad * 8];
            }
#pragma unroll
            for (int tt = 0; tt < 4; ++tt) {
                int cc = wn * 64 + tt * 16 + l16;
                s16x8 bh = *(s16x8*)&Bh[cc * 72 + c * 32 + quad * 8];
                s16x8 bl = *(s16x8*)&Bl[cc * 72 + c * 32 + quad * 8];
#pragma unroll
                for (int mt = 0; mt < 2; ++mt) {
                    acc[mt][tt] = MFMA(ah[mt], bh, acc[mt][tt]);
                    acc[mt][tt] = MFMA(ah[mt], bl, acc[mt][tt]);
                    if (wn == 0) acc[mt][tt] = MFMA(al[mt], bh, acc[mt][tt]);
                }
            }
        }
#pragma unroll
        for (int mt = 0; mt < 2; ++mt)
#pragma unroll
            for (int tt = 0; tt < 4; ++tt) {
                int col = wn * 64 + tt * 16 + l16;
#pragma unroll
                for (int r = 0; r < 4; ++r) {
                    int row = rows0 + wm * 32 + mt * 16 + quad * 4 + r;
                    if (row >= N) continue;
                    float v = acc[mt][tt][r];
                    if (col < 64) Ph[(size_t)row * 64 + col] = f2bf(v + pre_b[col]);
                    else          Qh[(size_t)row * 64 + (col - 64)] = f2bf(v);
                }
            }
    }
}

// ---------------- per-layer kernels ----------------

// aggregation v4 (round-3 proven): one wave = 4 nodes; padded CSR, branch-free body.
__global__ __launch_bounds__(256) void k_agg(const u16* __restrict__ Ph,
                                             const u16* __restrict__ Qh,
                                             const int* __restrict__ offs,
                                             const int* __restrict__ degp,
                                             const u16* __restrict__ ss,
                                             u16* __restrict__ AGGh, int N) {
    int w = threadIdx.x >> 6, lane = threadIdx.x & 63;
    int g = lane >> 4;              // node sub-slot 0..3
    int f4b = (lane & 15) << 3;     // byte offset of this lane's 4 features
    int node = blockIdx.x * 16 + w * 4 + g;
    int nc = min(node, N - 1);
    int beg = offs[nc];
    int d = (node < N) ? degp[nc] : 0;
    int dP = (d + 3) & ~3;
    int end = beg + dP;
    int mdP = dP;
    mdP = max(mdP, __shfl_xor(mdP, 16));
    mdP = max(mdP, __shfl_xor(mdP, 32));
    int trips = mdP >> 2;

    float sum0 = 0.f, sum1 = 0.f, sum2 = 0.f, sum3 = 0.f;
    float sq0 = 0.f, sq1 = 0.f, sq2 = 0.f, sq3 = 0.f;
    float mx0 = -3.4e38f, mx1 = -3.4e38f, mx2 = -3.4e38f, mx3 = -3.4e38f;
    float mn0 = 3.4e38f, mn1 = 3.4e38f, mn2 = 3.4e38f, mn3 = 3.4e38f;

    const char* qbase = (const char*)Qh;

#define ACC4(LO, HI)                                                        \
    {                                                                       \
        float q0 = __uint_as_float((LO) << 16);                             \
        float q1 = __uint_as_float((LO) & 0xFFFF0000u);                     \
        float q2 = __uint_as_float((HI) << 16);                             \
        float q3 = __uint_as_float((HI) & 0xFFFF0000u);                     \
        sum0 += q0; sq0 = fmaf(q0, q0, sq0);                                \
        mx0 = fmaxf(mx0, q0); mn0 = fminf(mn0, q0);                         \
        sum1 += q1; sq1 = fmaf(q1, q1, sq1);                                \
        mx1 = fmaxf(mx1, q1); mn1 = fminf(mn1, q1);                         \
        sum2 += q2; sq2 = fmaf(q2, q2, sq2);                                \
        mx2 = fmaxf(mx2, q2); mn2 = fminf(mn2, q2);                         \
        sum3 += q3; sq3 = fmaf(q3, q3, sq3);                                \
        mx3 = fmaxf(mx3, q3); mn3 = fminf(mn3, q3);                         \
    }

    int e = beg;
    for (int it = 0; it < trips; ++it, e += 4) {
        if (e < end) {
            uint2 sw = *(const uint2*)(ss + e);  // 4 packed src ids
            unsigned a0 = ((sw.x & 0xFFFFu) << 7) | (unsigned)f4b;
            unsigned a1 = ((sw.x >> 16) << 7) | (unsigned)f4b;
            unsigned a2 = ((sw.y & 0xFFFFu) << 7) | (unsigned)f4b;
            unsigned a3 = ((sw.y >> 16) << 7) | (unsigned)f4b;
            uint2 qa = *(const uint2*)(qbase + a0);
            uint2 qb = *(const uint2*)(qbase + a1);
            uint2 qc = *(const uint2*)(qbase + a2);
            uint2 qd = *(const uint2*)(qbase + a3);
            ACC4(qa.x, qa.y);
            ACC4(qb.x, qb.y);
            ACC4(qc.x, qc.y);
            ACC4(qd.x, qd.y);
        }
    }
#undef ACC4

    if (d & 3) {
        unsigned sl = ss[beg + d - 1];
        uint2 ql = *(const uint2*)(qbase + ((sl << 7) | (unsigned)f4b));
        float padf = (float)(dP - d);
        float qL0 = __uint_as_float(ql.x << 16);
        float qL1 = __uint_as_float(ql.x & 0xFFFF0000u);
        float qL2 = __uint_as_float(ql.y << 16);
        float qL3 = __uint_as_float(ql.y & 0xFFFF0000u);
        float t0 = padf * qL0, t1 = padf * qL1, t2 = padf * qL2, t3 = padf * qL3;
        sum0 -= t0; sq0 = fmaf(-t0, qL0, sq0);
        sum1 -= t1; sq1 = fmaf(-t1, qL1, sq1);
        sum2 -= t2; sq2 = fmaf(-t2, qL2, sq2);
        sum3 -= t3; sq3 = fmaf(-t3, qL3, sq3);
    }

    float dc = fmaxf((float)d, 1.f);
    float inv = 1.0f / dc;
    float e0 = sum0 * inv, e1 = sum1 * inv, e2 = sum2 * inv, e3 = sum3 * inv;
    float sd0 = sqrtf(fmaxf(fmaf(-e0, e0, sq0 * inv), 0.f) + EPSV);
    float sd1 = sqrtf(fmaxf(fmaf(-e1, e1, sq1 * inv), 0.f) + EPSV);
    float sd2 = sqrtf(fmaxf(fmaf(-e2, e2, sq2 * inv), 0.f) + EPSV);
    float sd3 = sqrtf(fmaxf(fmaf(-e3, e3, sq3 * inv), 0.f) + EPSV);

    uint2 pw = *(const uint2*)((const char*)Ph + (((unsigned)nc << 7) | (unsigned)f4b));
    float p0 = __uint_as_float(pw.x << 16), p1 = __uint_as_float(pw.x & 0xFFFF0000u);
    float p2 = __uint_as_float(pw.y << 16), p3 = __uint_as_float(pw.y & 0xFFFF0000u);

    bool he = d > 0;
    float m0 = he ? p0 + e0 : 0.f, m1 = he ? p1 + e1 : 0.f;
    float m2 = he ? p2 + e2 : 0.f, m3 = he ? p3 + e3 : 0.f;
    float X0 = he ? p0 + mx0 : 0.f, X1 = he ? p1 + mx1 : 0.f;
    float X2 = he ? p2 + mx2 : 0.f, X3 = he ? p3 + mx3 : 0.f;
    float n0 = he ? p0 + mn0 : 0.f, n1 = he ? p1 + mn1 : 0.f;
    float n2 = he ? p2 + mn2 : 0.f, n3 = he ? p3 + mn3 : 0.f;

    if (node < N) {
        u16* out = (u16*)((char*)AGGh + (((unsigned)node << 9) | (unsigned)f4b));
        *(u16x4*)(out)       = (u16x4){f2bf(m0), f2bf(m1), f2bf(m2), f2bf(m3)};
        *(u16x4*)(out + 64)  = (u16x4){f2bf(X0), f2bf(X1), f2bf(X2), f2bf(X3)};
        *(u16x4*)(out + 128) = (u16x4){f2bf(n0), f2bf(n1), f2bf(n2), f2bf(n3)};
        *(u16x4*)(out + 192) = (u16x4){f2bf(sd0), f2bf(sd1), f2bf(sd2), f2bf(sd3)};
    }
}

// gemm2 v7: r10's 64k-chunk 2-barrier schedule, but ALL pure-copy staging is
// async global_load_lds (no VGPR round-trip, no ds_writes) into a LINEAR
// pitch-64 LDS tile; bank-conflict-freedom via both-sides XOR swizzle:
// LDS (r,s) holds global (r, s^(r&7)); gload_lds sources are pre-swizzled,
// all reads/writes use swzi(). MFMA sequence/operands bit-identical to r10.
// OOB A-rows: clamped duplicate rows (outputs unstored). LDS 80KB.
__global__ __launch_bounds__(512) void k_gemm2(const float* __restrict__ hIn,
                                               const u16* __restrict__ AGGh,
                                               const u16* __restrict__ WT_hi,
                                               const u16* __restrict__ WT_lo,
                                               const float* __restrict__ bpp,
                                               const int* __restrict__ degp,
                                               const float* __restrict__ lsum,
                                               float* __restrict__ hOut,
                                               int doNext,
                                               const u16* __restrict__ WpN_hi,
                                               const u16* __restrict__ WpN_lo,
                                               const float* __restrict__ pre_bN,
                                               u16* __restrict__ PhN,
                                               u16* __restrict__ QhN, int M) {
    __shared__ __align__(16) u16 S[40960];  // 80KB
    const int AHo = 0;       // A-hi: 128 rows x 64
    const int ALo = 8192;    // A-lo: 128 rows (phase1 + phaseC)
    const int BHo = 16384;   // B-hi: 192 rows
    const int BLo = 28672;   // B-lo: 192 rows
    int t = threadIdx.x, wid = t >> 6, lane = t & 63;
    int rows0 = blockIdx.x * 128;
    int quad = lane >> 4, l16 = lane & 15;
    int wm = wid & 3, wn = wid >> 2;
    int lr8 = lane >> 3, ls = lane & 7;  // gload_lds source decomposition

    f32x4 acc[2][6];  // [mt][cg + third*2]
#pragma unroll
    for (int mt = 0; mt < 2; ++mt)
#pragma unroll
        for (int tt = 0; tt < 6; ++tt) acc[mt][tt] = (f32x4){0.f, 0.f, 0.f, 0.f};

    // ---- Phase 1: k 0..63 over hIn (hi/lo split), cols 0:64 ----
#pragma unroll
    for (int it = 0; it < 2; ++it) {  // A: reg-staged (f32->hi/lo transform), swizzled writes
        int task = it * 512 + t;
        int r = task >> 3, seg = task & 7;
        int row = rows0 + r;
        float4 v0 = make_float4(0.f, 0.f, 0.f, 0.f), v1 = v0;
        if (row < M) {
            v0 = *(const float4*)&hIn[(size_t)row * 64 + seg * 8];
            v1 = *(const float4*)&hIn[(size_t)row * 64 + seg * 8 + 4];
        }
        s16x8 hv, lv;
        split8(v0, v1, hv, lv);
        *(s16x8*)&S[AHo + swzi(r, seg)] = hv;
        *(s16x8*)&S[ALo + swzi(r, seg)] = lv;
    }
    {  // B1: 64 cols x k0..63 via gload_lds, 1KB/call, 1 hi + 1 lo per wave
        int r = wid * 8 + lr8;
        int sx = ls ^ (r & 7);
        gll(WT_hi + (size_t)r * 320 + sx * 8, &S[BHo + wid * 512]);
        gll(WT_lo + (size_t)r * 320 + sx * 8, &S[BLo + wid * 512]);
    }
    __syncthreads();
#pragma unroll
    for (int half = 0; half < 2; ++half) {
        int s = half * 4 + quad;
        s16x8 ah[2], al[2];
#pragma unroll
        for (int mt = 0; mt < 2; ++mt) {
            int r = wm * 32 + mt * 16 + l16;
            ah[mt] = *(s16x8*)&S[AHo + swzi(r, s)];
            al[mt] = *(s16x8*)&S[ALo + swzi(r, s)];
        }
#pragma unroll
        for (int cg = 0; cg < 2; ++cg) {
            int cc = wn * 32 + cg * 16 + l16;
            s16x8 bh = *(s16x8*)&S[BHo + swzi(cc, s)];
            s16x8 bl = *(s16x8*)&S[BLo + swzi(cc, s)];
#pragma unroll
            for (int mt = 0; mt < 2; ++mt) {
                acc[mt][cg] = MFMA(ah[mt], bh, acc[mt][cg]);
                acc[mt][cg] = MFMA(al[mt], bh, acc[mt][cg]);
                acc[mt][cg] = MFMA(ah[mt], bl, acc[mt][cg]);
            }
        }
    }

    // ---- Phase 2: k 64..319 over AGGh, 4 chunks of 64-k, all 192 cols ----
    for (int chunk = 0; chunk < 4; ++chunk) {
        __syncthreads();  // previous chunk's LDS reads complete
#pragma unroll
        for (int j = 0; j < 2; ++j) {  // A (hi only): 128 rows, 2 calls/wave
            int rb = (wid + j * 8) * 8;
            int r = rb + lr8;
            int rowc = min(rows0 + r, M - 1);
            int sx = ls ^ (r & 7);
            gll(AGGh + (size_t)rowc * 256 + chunk * 64 + sx * 8, &S[AHo + rb * 64]);
        }
#pragma unroll
        for (int j = 0; j < 3; ++j) {  // B: 192 cols, 3 hi + 3 lo calls/wave
            int rb = (wid * 3 + j) * 8;
            int r = rb + lr8;
            int sx = ls ^ (r & 7);
            size_t go = (size_t)r * 320 + 64 + chunk * 64 + sx * 8;
            gll(WT_hi + go, &S[BHo + rb * 64]);
            gll(WT_lo + go, &S[BLo + rb * 64]);
        }
        __syncthreads();
#pragma unroll
        for (int half = 0; half < 2; ++half) {
            int s = half * 4 + quad;
            s16x8 ah[2];
#pragma unroll
            for (int mt = 0; mt < 2; ++mt) {
                int r = wm * 32 + mt * 16 + l16;
                ah[mt] = *(s16x8*)&S[AHo + swzi(r, s)];
            }
#pragma unroll
            for (int tt = 0; tt < 6; ++tt) {
                int cc = wn * 32 + (tt & 1) * 16 + (tt >> 1) * 64 + l16;
                s16x8 bh = *(s16x8*)&S[BHo + swzi(cc, s)];
                s16x8 bl = *(s16x8*)&S[BLo + swzi(cc, s)];
#pragma unroll
                for (int mt = 0; mt < 2; ++mt) {
                    acc[mt][tt] = MFMA(ah[mt], bh, acc[mt][tt]);
                    acc[mt][tt] = MFMA(ah[mt], bl, acc[mt][tt]);
                }
            }
        }
    }

    // ---- Epilogue: combine thirds (amp/att inline), residual + bias ----
    float hv[2][2][4];
    float avg = *lsum / (float)M;
#pragma unroll
    for (int mt = 0; mt < 2; ++mt)
#pragma unroll
        for (int r = 0; r < 4; ++r) {
            int row = rows0 + wm * 32 + mt * 16 + quad * 4 + r;
            float am = 1.f, at = 1.f, hin0 = 0.f, hin1 = 0.f;
            if (row < M) {
                float dc = fmaxf((float)degp[row], 1.f);
                float ld = logf(dc + 1.f);
                am = ld / avg;
                at = avg / ld;
                hin0 = hIn[(size_t)row * 64 + wn * 32 + l16];
                hin1 = hIn[(size_t)row * 64 + wn * 32 + 16 + l16];
            }
#pragma unroll
            for (int cg = 0; cg < 2; ++cg) {
                int col = wn * 32 + cg * 16 + l16;
                float v = acc[mt][cg][r] + am * acc[mt][cg + 2][r] + at * acc[mt][cg + 4][r]
                        + (cg == 0 ? hin0 : hin1) + bpp[col];
                hv[mt][cg][r] = v;
                if (row < M) hOut[(size_t)row * 64 + col] = v;
            }
        }

    // ---- Phase C (doNext): gemm1(l+1) from in-register h' ----
    if (doNext) {
        __syncthreads();  // all phase-2 LDS reads complete before overwrite
#pragma unroll
        for (int j = 0; j < 2; ++j) {  // WpN: 128 cols, 2 hi + 2 lo calls/wave
            int rb = (wid + j * 8) * 8;
            int r = rb + lr8;
            int sx = ls ^ (r & 7);
            gll(WpN_hi + (size_t)r * 64 + sx * 8, &S[BHo + rb * 64]);
            gll(WpN_lo + (size_t)r * 64 + sx * 8, &S[BLo + rb * 64]);
        }
        // stage h' (scalar swizzled writes; each thread's own 16 elements)
#pragma unroll
        for (int mt = 0; mt < 2; ++mt)
#pragma unroll
            for (int cg = 0; cg < 2; ++cg) {
                int lc = wn * 32 + cg * 16 + l16;  // k-index 0..63
                int s = lc >> 3, b = lc & 7;
#pragma unroll
                for (int r = 0; r < 4; ++r) {
                    int rl = wm * 32 + mt * 16 + quad * 4 + r;
                    float v = hv[mt][cg][r];
                    u16 hi = f2bf(v);
                    int o = rl * 64 + ((s ^ (rl & 7)) << 3) + b;
                    S[AHo + o] = hi;
                    S[ALo + o] = f2bf(v - bf2f(hi));
                }
            }
        __syncthreads();

        f32x4 acc2[2][4];
#pragma unroll
        for (int mt = 0; mt < 2; ++mt)
#pragma unroll
            for (int tt = 0; tt < 4; ++tt) acc2[mt][tt] = (f32x4){0.f, 0.f, 0.f, 0.f};

#pragma unroll
        for (int half = 0; half < 2; ++half) {
            int s = half * 4 + quad;
            s16x8 ah[2], al[2];
#pragma unroll
            for (int mt = 0; mt < 2; ++mt) {
                int r = wm * 32 + mt * 16 + l16;
                ah[mt] = *(s16x8*)&S[AHo + swzi(r, s)];
                al[mt] = *(s16x8*)&S[ALo + swzi(r, s)];
            }
#pragma unroll
            for (int tt = 0; tt < 4; ++tt) {
                int cc = wn * 64 + tt * 16 + l16;
                s16x8 bh = *(s16x8*)&S[BHo + swzi(cc, s)];
                s16x8 bl = *(s16x8*)&S[BLo + swzi(cc, s)];
#pragma unroll
                for (int mt = 0; mt < 2; ++mt) {
                    acc2[mt][tt] = MFMA(ah[mt], bh, acc2[mt][tt]);
                    acc2[mt][tt] = MFMA(ah[mt], bl, acc2[mt][tt]);
                    if (wn == 0) acc2[mt][tt] = MFMA(al[mt], bh, acc2[mt][tt]);
                }
            }
        }

#pragma unroll
        for (int mt = 0; mt < 2; ++mt)
#pragma unroll
            for (int tt = 0; tt < 4; ++tt) {
                int col = wn * 64 + tt * 16 + l16;
#pragma unroll
                for (int r = 0; r < 4; ++r) {
                    int row = rows0 + wm * 32 + mt * 16 + quad * 4 + r;
                    if (row >= M) continue;
                    float v = acc2[mt][tt][r];
                    if (col < 64) PhN[(size_t)row * 64 + col] = f2bf(v + pre_bN[col]);
                    else          QhN[(size_t)row * 64 + (col - 64)] = f2bf(v);
                }
            }
    }
}

// ---------------- launch ----------------

extern "C" void kernel_launch(void* const* d_in, const int* in_sizes, int n_in,
                              void* d_out, int out_size, void* d_ws, size_t ws_size,
                              hipStream_t stream) {
    const float* x      = (const float*)d_in[0];
    const int*   ei     = (const int*)d_in[1];
    const float* pre_w  = (const float*)d_in[2];
    const float* pre_b  = (const float*)d_in[3];
    const float* post_w = (const float*)d_in[4];
    const float* post_b = (const float*)d_in[5];
    const float* lin_w  = (const float*)d_in[6];
    const float* lin_b  = (const float*)d_in[7];

    const int N = in_sizes[0] / 64;
    const int E = in_sizes[1] / 2;
    const int L = in_sizes[2] / (128 * 64);

    const int* srcIdx = ei;
    const int* dstIdx = ei + E;

    char* ws = (char*)d_ws;
    size_t off = 0;
    auto alloc = [&](size_t bytes) {
        void* p = ws + off;
        off += (bytes + 255) & ~(size_t)255;
        return p;
    };
    int*      deg        = (int*)alloc((size_t)N * 4);
    int*      offs       = (int*)alloc((size_t)(N + 1) * 4);
    u16*      srcSorted  = (u16*)alloc((size_t)NBP * CAPS * 2);
    unsigned* edgeTmp    = (unsigned*)alloc((size_t)NBP * CAP * 4);
    int*      bucketCur  = (int*)alloc(NBP * 4);
    float*    lsum       = (float*)alloc(256);
    u16*      WpT_hi     = (u16*)alloc((size_t)L * 128 * 64 * 2);
    u16*      WpT_lo     = (u16*)alloc((size_t)L * 128 * 64 * 2);
    u16*      WT_hi      = (u16*)alloc((size_t)L * 192 * 320 * 2);
    u16*      WT_lo      = (u16*)alloc((size_t)L * 192 * 320 * 2);
    float*    bpp        = (float*)alloc((size_t)L * 64 * 4);
    u16*      Ph         = (u16*)alloc((size_t)N * 64 * 2);
    u16*      Qh         = (u16*)alloc((size_t)N * 64 * 2);
    u16*      AGGh       = (u16*)alloc((size_t)N * 256 * 2);
    float*    hA         = (float*)alloc((size_t)N * 64 * 4);
    float*    hB         = (float*)alloc((size_t)N * 64 * 4);
    (void)ws_size;

    int NB = (N + 255) >> 8;
    int NB1 = (E + EPB3 - 1) / EPB3;
    int gblk = (N + 63) / 64;
    int gblk2 = (N + 127) / 128;

    hipMemsetAsync(bucketCur, 0, NBP * 4, stream);
    hipMemsetAsync(lsum, 0, 4, stream);

    k_pre1<<<NB1 + 449 * L, 512, 0, stream>>>(
        srcIdx, dstIdx, E, bucketCur, edgeTmp,
        pre_w, post_w, post_b, lin_w, lin_b,
        WpT_hi, WpT_lo, WT_hi, WT_lo, bpp, NB1);

    k_pre2<<<NB + gblk, 512, 0, stream>>>(
        edgeTmp, bucketCur, deg, offs, lsum, srcSorted,
        x, WpT_hi, WpT_lo, pre_b, Ph, Qh, N, E, NB);

    const float* hIn = x;
    float* hbuf[2] = {hA, hB};
    for (int l = 0; l < L; ++l) {
        float* hOut = (l == L - 1) ? (float*)d_out : hbuf[l & 1];
        int dn = (l < L - 1) ? 1 : 0;
        int ln = dn ? (l + 1) : 0;
        k_agg<<<(N + 15) / 16, 256, 0, stream>>>(Ph, Qh, offs, deg, srcSorted, AGGh, N);
        k_gemm2<<<gblk2, 512, 0, stream>>>(hIn, AGGh,
                                           WT_hi + (size_t)l * 192 * 320,
                                           WT_lo + (size_t)l * 192 * 320,
                                           bpp + (size_t)l * 64,
                                           deg, lsum, hOut, dn,
                                           WpT_hi + (size_t)ln * 128 * 64,
                                           WpT_lo + (size_t)ln * 128 * 64,
                                           pre_b + (size_t)ln * 64,
                                           Ph, Qh, N);
        hIn = hOut;
    }
}

// Round 13
// 248.120 us; speedup vs baseline: 1.2559x; 1.0206x over previous
//
#include <hip/hip_runtime.h>
#include <math.h>

#define EPSV 1e-5f
#define EPB3 4096  // edges per bucket-pass block (196 blocks, proven config)
#define NBP 256    // buckets of 256 nodes (N <= 65536; src packed in 16 bits)
#define CAP 6144   // per-bucket edgeTmp slab capacity (mean ~4081, +32 sigma)
#define CAPS (CAP + 768)  // padded sorted-slab capacity (pad <=3 per node)

typedef short s16x8 __attribute__((ext_vector_type(8)));
typedef float f32x4 __attribute__((ext_vector_type(4)));
typedef float f32x2 __attribute__((ext_vector_type(2)));
typedef unsigned short u16;
typedef unsigned short u16x4 __attribute__((ext_vector_type(4)));

#define MFMA(a, b, c) __builtin_amdgcn_mfma_f32_16x16x32_bf16(a, b, c, 0, 0, 0)

__device__ inline u16 f2bf(float f) {
    unsigned u = __float_as_uint(f);
    return (u16)((u + 0x7FFF + ((u >> 16) & 1)) >> 16);
}
__device__ inline float bf2f(u16 h) { return __uint_as_float(((unsigned)h) << 16); }

__device__ inline void split8(const float4& a, const float4& b, s16x8& hv, s16x8& lv) {
    float f[8] = {a.x, a.y, a.z, a.w, b.x, b.y, b.z, b.w};
#pragma unroll
    for (int i = 0; i < 8; ++i) {
        u16 h = f2bf(f[i]);
        hv[i] = (short)h;
        lv[i] = (short)f2bf(f[i] - bf2f(h));
    }
}

// async global->LDS, 16B per lane; LDS dest = wave-uniform base + lane*16.
typedef const __attribute__((address_space(1))) unsigned int* gp_t;
typedef __attribute__((address_space(3))) unsigned int* lp_t;
__device__ inline void gll(const void* g, void* l) {
    __builtin_amdgcn_global_load_lds((gp_t)g, (lp_t)l, 16, 0, 0);
}

// swizzled u16 index within a pitch-64 tile: row r, 16B-chunk s (0..7)
__device__ inline int swzi(int r, int s) { return r * 64 + ((s ^ (r & 7)) << 3); }

// ---------------- pre1: bucket partition + weight prep (merged) ----------------
__global__ __launch_bounds__(512) void k_pre1(
    const int* __restrict__ src, const int* __restrict__ dst, int E,
    int* __restrict__ bucketCursor, unsigned* __restrict__ edgeTmp,
    const float* __restrict__ pre_w, const float* __restrict__ post_w,
    const float* __restrict__ post_b, const float* __restrict__ lin_w,
    const float* __restrict__ lin_b, u16* __restrict__ WpT_hi,
    u16* __restrict__ WpT_lo, u16* __restrict__ WT_hi, u16* __restrict__ WT_lo,
    float* __restrict__ bpp, int NB1) {
    __shared__ int cnt[NBP], loff[NBP], lpos[NBP], gbase[NBP], sbuf[NBP];
    __shared__ unsigned stage[EPB3];
    int t = threadIdx.x;
    if ((int)blockIdx.x < NB1) {
        int base = blockIdx.x * EPB3;
        int cntE = min(EPB3, E - base);
        if (t < NBP) cnt[t] = 0;
        __syncthreads();
        unsigned ed[8];
#pragma unroll
        for (int j = 0; j < 8; ++j) {
            int idx = j * 512 + t;
            if (idx < cntE) {
                int e = base + idx;
                unsigned s = (unsigned)src[e];
                unsigned d = (unsigned)dst[e];
                ed[j] = ((d >> 8) << 24) | ((d & 255u) << 16) | s;
                atomicAdd(&cnt[d >> 8], 1);
            } else ed[j] = 0xFFFFFFFFu;
        }
        __syncthreads();
        if (t < NBP) sbuf[t] = cnt[t];
        __syncthreads();
        for (int o = 1; o < NBP; o <<= 1) {
            int v = 0;
            if (t < NBP && t >= o) v = sbuf[t - o];
            __syncthreads();
            if (t < NBP) sbuf[t] += v;
            __syncthreads();
        }
        if (t < NBP) {
            loff[t] = sbuf[t] - cnt[t];
            lpos[t] = sbuf[t] - cnt[t];
            gbase[t] = (cnt[t] > 0) ? atomicAdd(&bucketCursor[t], cnt[t]) : 0;
        }
        __syncthreads();
#pragma unroll
        for (int j = 0; j < 8; ++j) {
            if (ed[j] != 0xFFFFFFFFu) {
                int b = ed[j] >> 24;
                int p = atomicAdd(&lpos[b], 1);
                stage[p] = ed[j];
            }
        }
        __syncthreads();
        for (int i = t; i < cntE; i += 512) {
            unsigned pr = stage[i];
            int b = pr >> 24;
            int pos = gbase[b] + (i - loff[b]);
            if (pos < CAP) edgeTmp[(size_t)b * CAP + pos] = pr;
        }
        return;
    }
    int wq = blockIdx.x - NB1;
    int l = wq / 449;
    int bx = wq - l * 449;
    if (bx < 320) {
        if (t < 192) {
            int k = bx, j = t;
            int third = j >> 6, c = j & 63;
            float out = 0.f;
            int r = -1;
            if (k < 64) r = (third == 0) ? k : -1;
            else        r = 64 + third * 256 + (k - 64);
            if (r >= 0) {
                const float* pw = post_w + (size_t)(l * 832 + r) * 64;
                const float* lw = lin_w + (size_t)l * 64 * 64;
                float s = 0.f;
                for (int kk = 0; kk < 64; ++kk) s += pw[kk] * lw[kk * 64 + c];
                out = s;
            }
            u16 h = f2bf(out);
            size_t o = ((size_t)l * 192 + j) * 320 + k;
            WT_hi[o] = h;
            WT_lo[o] = f2bf(out - bf2f(h));
        }
    } else if (bx < 448) {
        if (t < 64) {
            int c = bx - 320, k = t;
            float v = pre_w[(size_t)l * 8192 + (size_t)(k + (c >= 64 ? 64 : 0)) * 64 + (c & 63)];
            u16 h = f2bf(v);
            size_t o = ((size_t)l * 128 + c) * 64 + k;
            WpT_hi[o] = h;
            WpT_lo[o] = f2bf(v - bf2f(h));
        }
    } else {
        if (t < 64) {
            int c = t;
            const float* pb = post_b + l * 64;
            const float* lw = lin_w + (size_t)l * 64 * 64;
            float s = lin_b[l * 64 + c];
            for (int k = 0; k < 64; ++k) s += pb[k] * lw[k * 64 + c];
            bpp[l * 64 + c] = s;
        }
    }
}

// ---------------- pre2: counting-sort + layer-0 gemm1 (merged) ----------------
__global__ __launch_bounds__(512) void k_pre2(
    const unsigned* __restrict__ edgeTmp, const int* __restrict__ bucketCur,
    int* __restrict__ deg, int* __restrict__ offs, float* __restrict__ lsum,
    u16* __restrict__ srcSorted,
    const float* __restrict__ x, const u16* __restrict__ WpT_hi,
    const u16* __restrict__ WpT_lo, const float* __restrict__ pre_b,
    u16* __restrict__ Ph, u16* __restrict__ Qh,
    int N, int E, int NB) {
    __shared__ __align__(16) char smem[55296];
    int t = threadIdx.x;
    if ((int)blockIdx.x < NB) {
        int* scnt = (int*)smem;
        int* sbuf = (int*)(smem + 1024);
        int* lcur = (int*)(smem + 2048);
        int* lofs = (int*)(smem + 3072);
        float* fred = (float*)(smem + 4096);
        u16* stageSrc = (u16*)(smem + 5120);
        int* cntPs = (int*)(smem + 5120 + CAPS * 2);
        int b = blockIdx.x;
        int n0 = b << 8;
        int nodes = min(256, N - n0);
        if (t < NBP) { lcur[t] = 0; scnt[t] = 0; }
        __syncthreads();
        int cnt = min(bucketCur[b], CAP);
        const unsigned* ebase = edgeTmp + (size_t)b * CAP;
        for (int i = t; i < cnt; i += 512) atomicAdd(&lcur[(ebase[i] >> 16) & 255], 1);
        __syncthreads();
        float ls = 0.f;
        int d = 0, dP = 0;
        if (t < nodes) {
            d = lcur[t];
            deg[n0 + t] = d;
            ls = logf(fmaxf((float)d, 1.f) + 1.f);
            dP = (d + 3) & ~3;
        }
        if (t < 256) fred[t] = ls;
        if (t < NBP) sbuf[t] = dP;
        __syncthreads();
        for (int o = 1; o < NBP; o <<= 1) {
            int v = 0;
            if (t < NBP && t >= o) v = sbuf[t - o];
            __syncthreads();
            if (t < NBP) sbuf[t] += v;
            __syncthreads();
        }
        if (t < NBP) lofs[t] = sbuf[t] - dP;
        if (t < nodes) offs[n0 + t] = b * CAPS + (sbuf[t] - dP);
        if (t == NBP - 1) *cntPs = sbuf[t];
        __syncthreads();
        for (int o = 128; o > 0; o >>= 1) {
            if (t < o) fred[t] += fred[t + o];
            __syncthreads();
        }
        if (t == 0) atomicAdd(lsum, fred[0]);
        for (int i = t; i < cnt; i += 512) {
            unsigned p = ebase[i];
            int dl = (p >> 16) & 255;
            int r = atomicAdd(&scnt[dl], 1);
            stageSrc[lofs[dl] + r] = (u16)(p & 0xFFFFu);
        }
        __syncthreads();
        if (t < nodes && (d & 3)) {
            int lp = lofs[t];
            u16 lastv = stageSrc[lp + d - 1];
            for (int k = d; k < dP; ++k) stageSrc[lp + k] = lastv;
        }
        __syncthreads();
        int cntP = *cntPs;
        for (int i = t; i < cntP; i += 512) srcSorted[(size_t)b * CAPS + i] = stageSrc[i];
        return;
    }
    // ---- gemm1 body: 64 rows, threads 0..255, ONE hoisted barrier ----
    u16* Ah = (u16*)smem;            // 64*72 u16 = 9216 B
    u16* Al = (u16*)(smem + 9216);
    u16* Bh = (u16*)(smem + 18432);  // 128*72 u16 = 18432 B
    u16* Bl = (u16*)(smem + 36864);
    int rows0 = ((int)blockIdx.x - NB) * 64;
    int wid = t >> 6, lane = t & 63;
    int quad = lane >> 4, l16 = lane & 15;
    int wm = wid & 1, wn = wid >> 1;
    if (t < 256) {
#pragma unroll
        for (int it = 0; it < 2; ++it) {
            int task = it * 256 + t;
            int r = task >> 3, seg = task & 7;
            int row = rows0 + r;
            float4 v0 = make_float4(0.f, 0.f, 0.f, 0.f), v1 = v0;
            if (row < N) {
                v0 = *(const float4*)&x[(size_t)row * 64 + seg * 8];
                v1 = *(const float4*)&x[(size_t)row * 64 + seg * 8 + 4];
            }
            s16x8 hv, lv;
            split8(v0, v1, hv, lv);
            *(s16x8*)&Ah[r * 72 + seg * 8] = hv;
            *(s16x8*)&Al[r * 72 + seg * 8] = lv;
        }
#pragma unroll
        for (int it = 0; it < 4; ++it) {
            int task = it * 256 + t;
            int c = task >> 3, seg = task & 7;
            *(s16x8*)&Bh[c * 72 + seg * 8] = *(const s16x8*)&WpT_hi[(size_t)c * 64 + seg * 8];
            *(s16x8*)&Bl[c * 72 + seg * 8] = *(const s16x8*)&WpT_lo[(size_t)c * 64 + seg * 8];
        }
    }
    __syncthreads();
    if (t < 256) {
        f32x4 acc[2][4];
#pragma unroll
        for (int mt = 0; mt < 2; ++mt)
#pragma unroll
            for (int tt = 0; tt < 4; ++tt) acc[mt][tt] = (f32x4){0.f, 0.f, 0.f, 0.f};
#pragma unroll
        for (int c = 0; c < 2; ++c) {
            s16x8 ah[2], al[2];
#pragma unroll
            for (int mt = 0; mt < 2; ++mt) {
                int r = wm * 32 + mt * 16 + l16;
                ah[mt] = *(s16x8*)&Ah[r * 72 + c * 32 + quad * 8];
                al[mt] = *(s16x8*)&Al[r * 72 + c * 32 + quad * 8];
            }
#pragma unroll
            for (int tt = 0; tt < 4; ++tt) {
                int cc = wn * 64 + tt * 16 + l16;
                s16x8 bh = *(s16x8*)&Bh[cc * 72 + c * 32 + quad * 8];
                s16x8 bl = *(s16x8*)&Bl[cc * 72 + c * 32 + quad * 8];
#pragma unroll
                for (int mt = 0; mt < 2; ++mt) {
                    acc[mt][tt] = MFMA(ah[mt], bh, acc[mt][tt]);
                    acc[mt][tt] = MFMA(ah[mt], bl, acc[mt][tt]);
                    if (wn == 0) acc[mt][tt] = MFMA(al[mt], bh, acc[mt][tt]);
                }
            }
        }
#pragma unroll
        for (int mt = 0; mt < 2; ++mt)
#pragma unroll
            for (int tt = 0; tt < 4; ++tt) {
                int col = wn * 64 + tt * 16 + l16;
#pragma unroll
                for (int r = 0; r < 4; ++r) {
                    int row = rows0 + wm * 32 + mt * 16 + quad * 4 + r;
                    if (row >= N) continue;
                    float v = acc[mt][tt][r];
                    if (col < 64) Ph[(size_t)row * 64 + col] = f2bf(v + pre_b[col]);
                    else          Qh[(size_t)row * 64 + (col - 64)] = f2bf(v);
                }
            }
    }
}

// ---------------- per-layer kernels ----------------

// aggregation v5: v4 structure with packed-f32 accumulation (float2 ext-vector
// -> v_pk_add_f32/v_pk_fma_f32 on gfx950; identical IEEE semantics & order).
__global__ __launch_bounds__(256) void k_agg(const u16* __restrict__ Ph,
                                             const u16* __restrict__ Qh,
                                             const int* __restrict__ offs,
                                             const int* __restrict__ degp,
                                             const u16* __restrict__ ss,
                                             u16* __restrict__ AGGh, int N) {
    int w = threadIdx.x >> 6, lane = threadIdx.x & 63;
    int g = lane >> 4;              // node sub-slot 0..3
    int f4b = (lane & 15) << 3;     // byte offset of this lane's 4 features
    int node = blockIdx.x * 16 + w * 4 + g;
    int nc = min(node, N - 1);
    int beg = offs[nc];
    int d = (node < N) ? degp[nc] : 0;
    int dP = (d + 3) & ~3;
    int end = beg + dP;
    int mdP = dP;
    mdP = max(mdP, __shfl_xor(mdP, 16));
    mdP = max(mdP, __shfl_xor(mdP, 32));
    int trips = mdP >> 2;

    f32x2 sum01 = {0.f, 0.f}, sum23 = {0.f, 0.f};
    f32x2 sq01 = {0.f, 0.f}, sq23 = {0.f, 0.f};
    f32x2 mx01 = {-3.4e38f, -3.4e38f}, mx23 = {-3.4e38f, -3.4e38f};
    f32x2 mn01 = {3.4e38f, 3.4e38f}, mn23 = {3.4e38f, 3.4e38f};

    const char* qbase = (const char*)Qh;

#define ACC4(LO, HI)                                                        \
    {                                                                       \
        f32x2 fa, fb;                                                       \
        fa.x = __uint_as_float((LO) << 16);                                 \
        fa.y = __uint_as_float((LO) & 0xFFFF0000u);                         \
        fb.x = __uint_as_float((HI) << 16);                                 \
        fb.y = __uint_as_float((HI) & 0xFFFF0000u);                         \
        sum01 += fa; sq01 = __builtin_elementwise_fma(fa, fa, sq01);        \
        mx01 = __builtin_elementwise_max(mx01, fa);                         \
        mn01 = __builtin_elementwise_min(mn01, fa);                         \
        sum23 += fb; sq23 = __builtin_elementwise_fma(fb, fb, sq23);        \
        mx23 = __builtin_elementwise_max(mx23, fb);                         \
        mn23 = __builtin_elementwise_min(mn23, fb);                         \
    }

    int e = beg;
    for (int it = 0; it < trips; ++it, e += 4) {
        if (e < end) {
            uint2 sw = *(const uint2*)(ss + e);  // 4 packed src ids
            unsigned a0 = ((sw.x & 0xFFFFu) << 7) | (unsigned)f4b;
            unsigned a1 = ((sw.x >> 16) << 7) | (unsigned)f4b;
            unsigned a2 = ((sw.y & 0xFFFFu) << 7) | (unsigned)f4b;
            unsigned a3 = ((sw.y >> 16) << 7) | (unsigned)f4b;
            uint2 qa = *(const uint2*)(qbase + a0);
            uint2 qb = *(const uint2*)(qbase + a1);
            uint2 qc = *(const uint2*)(qbase + a2);
            uint2 qd = *(const uint2*)(qbase + a3);
            ACC4(qa.x, qa.y);
            ACC4(qb.x, qb.y);
            ACC4(qc.x, qc.y);
            ACC4(qd.x, qd.y);
        }
    }
#undef ACC4

    if (d & 3) {  // subtract the (dP-d) duplicated pad edges from sum/sq
        unsigned sl = ss[beg + d - 1];
        uint2 ql = *(const uint2*)(qbase + ((sl << 7) | (unsigned)f4b));
        float padf = (float)(dP - d);
        f32x2 pf = {padf, padf};
        f32x2 fa, fb;
        fa.x = __uint_as_float(ql.x << 16);
        fa.y = __uint_as_float(ql.x & 0xFFFF0000u);
        fb.x = __uint_as_float(ql.y << 16);
        fb.y = __uint_as_float(ql.y & 0xFFFF0000u);
        f32x2 ta = pf * fa, tb = pf * fb;
        sum01 -= ta; sq01 = __builtin_elementwise_fma(-ta, fa, sq01);
        sum23 -= tb; sq23 = __builtin_elementwise_fma(-tb, fb, sq23);
    }

    float sum0 = sum01.x, sum1 = sum01.y, sum2 = sum23.x, sum3 = sum23.y;
    float sq0 = sq01.x, sq1 = sq01.y, sq2 = sq23.x, sq3 = sq23.y;
    float mx0 = mx01.x, mx1 = mx01.y, mx2 = mx23.x, mx3 = mx23.y;
    float mn0 = mn01.x, mn1 = mn01.y, mn2 = mn23.x, mn3 = mn23.y;

    float dc = fmaxf((float)d, 1.f);
    float inv = 1.0f / dc;
    float e0 = sum0 * inv, e1 = sum1 * inv, e2 = sum2 * inv, e3 = sum3 * inv;
    float sd0 = sqrtf(fmaxf(fmaf(-e0, e0, sq0 * inv), 0.f) + EPSV);
    float sd1 = sqrtf(fmaxf(fmaf(-e1, e1, sq1 * inv), 0.f) + EPSV);
    float sd2 = sqrtf(fmaxf(fmaf(-e2, e2, sq2 * inv), 0.f) + EPSV);
    float sd3 = sqrtf(fmaxf(fmaf(-e3, e3, sq3 * inv), 0.f) + EPSV);

    uint2 pw = *(const uint2*)((const char*)Ph + (((unsigned)nc << 7) | (unsigned)f4b));
    float p0 = __uint_as_float(pw.x << 16), p1 = __uint_as_float(pw.x & 0xFFFF0000u);
    float p2 = __uint_as_float(pw.y << 16), p3 = __uint_as_float(pw.y & 0xFFFF0000u);

    bool he = d > 0;
    float m0 = he ? p0 + e0 : 0.f, m1 = he ? p1 + e1 : 0.f;
    float m2 = he ? p2 + e2 : 0.f, m3 = he ? p3 + e3 : 0.f;
    float X0 = he ? p0 + mx0 : 0.f, X1 = he ? p1 + mx1 : 0.f;
    float X2 = he ? p2 + mx2 : 0.f, X3 = he ? p3 + mx3 : 0.f;
    float n0 = he ? p0 + mn0 : 0.f, n1 = he ? p1 + mn1 : 0.f;
    float n2 = he ? p2 + mn2 : 0.f, n3 = he ? p3 + mn3 : 0.f;

    if (node < N) {
        u16* out = (u16*)((char*)AGGh + (((unsigned)node << 9) | (unsigned)f4b));
        *(u16x4*)(out)       = (u16x4){f2bf(m0), f2bf(m1), f2bf(m2), f2bf(m3)};
        *(u16x4*)(out + 64)  = (u16x4){f2bf(X0), f2bf(X1), f2bf(X2), f2bf(X3)};
        *(u16x4*)(out + 128) = (u16x4){f2bf(n0), f2bf(n1), f2bf(n2), f2bf(n3)};
        *(u16x4*)(out + 192) = (u16x4){f2bf(sd0), f2bf(sd1), f2bf(sd2), f2bf(sd3)};
    }
}

// gemm2 v8: r12's proven gload_lds+swizzle kernel with LDS packed to exactly
// 64KB (phase-unioned: A-lo / B1 / BC regions overlap phase-2's B2 slabs,
// every overlap separated by an existing barrier) -> 2 blocks/CU co-residency
// to hide the per-chunk vmcnt(0) drain. MFMA sequence/operands unchanged.
__global__ __launch_bounds__(512) void k_gemm2(const float* __restrict__ hIn,
                                               const u16* __restrict__ AGGh,
                                               const u16* __restrict__ WT_hi,
                                               const u16* __restrict__ WT_lo,
                                               const float* __restrict__ bpp,
                                               const int* __restrict__ degp,
                                               const float* __restrict__ lsum,
                                               float* __restrict__ hOut,
                                               int doNext,
                                               const u16* __restrict__ WpN_hi,
                                               const u16* __restrict__ WpN_lo,
                                               const float* __restrict__ pre_bN,
                                               u16* __restrict__ PhN,
                                               u16* __restrict__ QhN, int M) {
    __shared__ __align__(16) u16 S[32768];  // 64KB phase-union
    const int AHo  = 0;      // A-hi 128x64 (all phases)
    const int ALo  = 8192;   // A-lo 128x64 (phase1/phaseC; overlaps B2h)
    const int B1Ho = 16384;  // phase1 B 64x64 hi
    const int B1Lo = 20480;  // phase1 B 64x64 lo
    const int B2Ho = 8192;   // phase2 B 192x64 hi (overlaps ALo+B1Ho)
    const int B2Lo = 20480;  // phase2 B 192x64 lo
    const int BCHo = 16384;  // phaseC B 128x64 hi
    const int BCLo = 24576;  // phaseC B 128x64 lo
    int t = threadIdx.x, wid = t >> 6, lane = t & 63;
    int rows0 = blockIdx.x * 128;
    int quad = lane >> 4, l16 = lane & 15;
    int wm = wid & 3, wn = wid >> 2;
    int lr8 = lane >> 3, ls = lane & 7;  // gload_lds source decomposition

    f32x4 acc[2][6];  // [mt][cg + third*2]
#pragma unroll
    for (int mt = 0; mt < 2; ++mt)
#pragma unroll
        for (int tt = 0; tt < 6; ++tt) acc[mt][tt] = (f32x4){0.f, 0.f, 0.f, 0.f};

    // ---- Phase 1: k 0..63 over hIn (hi/lo split), cols 0:64 ----
#pragma unroll
    for (int it = 0; it < 2; ++it) {  // A: reg-staged (f32->hi/lo transform), swizzled writes
        int task = it * 512 + t;
        int r = task >> 3, seg = task & 7;
        int row = rows0 + r;
        float4 v0 = make_float4(0.f, 0.f, 0.f, 0.f), v1 = v0;
        if (row < M) {
            v0 = *(const float4*)&hIn[(size_t)row * 64 + seg * 8];
            v1 = *(const float4*)&hIn[(size_t)row * 64 + seg * 8 + 4];
        }
        s16x8 hv, lv;
        split8(v0, v1, hv, lv);
        *(s16x8*)&S[AHo + swzi(r, seg)] = hv;
        *(s16x8*)&S[ALo + swzi(r, seg)] = lv;
    }
    {  // B1: 64 cols x k0..63 via gload_lds, 1KB/call, 1 hi + 1 lo per wave
        int r = wid * 8 + lr8;
        int sx = ls ^ (r & 7);
        gll(WT_hi + (size_t)r * 320 + sx * 8, &S[B1Ho + wid * 512]);
        gll(WT_lo + (size_t)r * 320 + sx * 8, &S[B1Lo + wid * 512]);
    }
    __syncthreads();
#pragma unroll
    for (int half = 0; half < 2; ++half) {
        int s = half * 4 + quad;
        s16x8 ah[2], al[2];
#pragma unroll
        for (int mt = 0; mt < 2; ++mt) {
            int r = wm * 32 + mt * 16 + l16;
            ah[mt] = *(s16x8*)&S[AHo + swzi(r, s)];
            al[mt] = *(s16x8*)&S[ALo + swzi(r, s)];
        }
#pragma unroll
        for (int cg = 0; cg < 2; ++cg) {
            int cc = wn * 32 + cg * 16 + l16;
            s16x8 bh = *(s16x8*)&S[B1Ho + swzi(cc, s)];
            s16x8 bl = *(s16x8*)&S[B1Lo + swzi(cc, s)];
#pragma unroll
            for (int mt = 0; mt < 2; ++mt) {
                acc[mt][cg] = MFMA(ah[mt], bh, acc[mt][cg]);
                acc[mt][cg] = MFMA(al[mt], bh, acc[mt][cg]);
                acc[mt][cg] = MFMA(ah[mt], bl, acc[mt][cg]);
            }
        }
    }

    // ---- Phase 2: k 64..319 over AGGh, 4 chunks of 64-k, all 192 cols ----
    for (int chunk = 0; chunk < 4; ++chunk) {
        __syncthreads();  // previous chunk's (or phase1's) LDS reads complete
#pragma unroll
        for (int j = 0; j < 2; ++j) {  // A (hi only): 128 rows, 2 calls/wave
            int rb = (wid + j * 8) * 8;
            int r = rb + lr8;
            int rowc = min(rows0 + r, M - 1);
            int sx = ls ^ (r & 7);
            gll(AGGh + (size_t)rowc * 256 + chunk * 64 + sx * 8, &S[AHo + rb * 64]);
        }
#pragma unroll
        for (int j = 0; j < 3; ++j) {  // B: 192 cols, 3 hi + 3 lo calls/wave
            int rb = (wid * 3 + j) * 8;
            int r = rb + lr8;
            int sx = ls ^ (r & 7);
            size_t go = (size_t)r * 320 + 64 + chunk * 64 + sx * 8;
            gll(WT_hi + go, &S[B2Ho + rb * 64]);
            gll(WT_lo + go, &S[B2Lo + rb * 64]);
        }
        __syncthreads();
#pragma unroll
        for (int half = 0; half < 2; ++half) {
            int s = half * 4 + quad;
            s16x8 ah[2];
#pragma unroll
            for (int mt = 0; mt < 2; ++mt) {
                int r = wm * 32 + mt * 16 + l16;
                ah[mt] = *(s16x8*)&S[AHo + swzi(r, s)];
            }
#pragma unroll
            for (int tt = 0; tt < 6; ++tt) {
                int cc = wn * 32 + (tt & 1) * 16 + (tt >> 1) * 64 + l16;
                s16x8 bh = *(s16x8*)&S[B2Ho + swzi(cc, s)];
                s16x8 bl = *(s16x8*)&S[B2Lo + swzi(cc, s)];
#pragma unroll
                for (int mt = 0; mt < 2; ++mt) {
                    acc[mt][tt] = MFMA(ah[mt], bh, acc[mt][tt]);
                    acc[mt][tt] = MFMA(ah[mt], bl, acc[mt][tt]);
                }
            }
        }
    }

    // ---- Epilogue: combine thirds (amp/att inline), residual + bias ----
    float hv[2][2][4];
    float avg = *lsum / (float)M;
#pragma unroll
    for (int mt = 0; mt < 2; ++mt)
#pragma unroll
        for (int r = 0; r < 4; ++r) {
            int row = rows0 + wm * 32 + mt * 16 + quad * 4 + r;
            float am = 1.f, at = 1.f, hin0 = 0.f, hin1 = 0.f;
            if (row < M) {
                float dc = fmaxf((float)degp[row], 1.f);
                float ld = logf(dc + 1.f);
                am = ld / avg;
                at = avg / ld;
                hin0 = hIn[(size_t)row * 64 + wn * 32 + l16];
                hin1 = hIn[(size_t)row * 64 + wn * 32 + 16 + l16];
            }
#pragma unroll
            for (int cg = 0; cg < 2; ++cg) {
                int col = wn * 32 + cg * 16 + l16;
                float v = acc[mt][cg][r] + am * acc[mt][cg + 2][r] + at * acc[mt][cg + 4][r]
                        + (cg == 0 ? hin0 : hin1) + bpp[col];
                hv[mt][cg][r] = v;
                if (row < M) hOut[(size_t)row * 64 + col] = v;
            }
        }

    // ---- Phase C (doNext): gemm1(l+1) from in-register h' ----
    if (doNext) {
        __syncthreads();  // all phase-2 LDS reads complete before overwrite
#pragma unroll
        for (int j = 0; j < 2; ++j) {  // WpN: 128 cols, 2 hi + 2 lo calls/wave
            int rb = (wid + j * 8) * 8;
            int r = rb + lr8;
            int sx = ls ^ (r & 7);
            gll(WpN_hi + (size_t)r * 64 + sx * 8, &S[BCHo + rb * 64]);
            gll(WpN_lo + (size_t)r * 64 + sx * 8, &S[BCLo + rb * 64]);
        }
        // stage h' (scalar swizzled writes; each thread's own 16 elements)
#pragma unroll
        for (int mt = 0; mt < 2; ++mt)
#pragma unroll
            for (int cg = 0; cg < 2; ++cg) {
                int lc = wn * 32 + cg * 16 + l16;  // k-index 0..63
                int s = lc >> 3, b = lc & 7;
#pragma unroll
                for (int r = 0; r < 4; ++r) {
                    int rl = wm * 32 + mt * 16 + quad * 4 + r;
                    float v = hv[mt][cg][r];
                    u16 hi = f2bf(v);
                    int o = rl * 64 + ((s ^ (rl & 7)) << 3) + b;
                    S[AHo + o] = hi;
                    S[ALo + o] = f2bf(v - bf2f(hi));
                }
            }
        __syncthreads();

        f32x4 acc2[2][4];
#pragma unroll
        for (int mt = 0; mt < 2; ++mt)
#pragma unroll
            for (int tt = 0; tt < 4; ++tt) acc2[mt][tt] = (f32x4){0.f, 0.f, 0.f, 0.f};

#pragma unroll
        for (int half = 0; half < 2; ++half) {
            int s = half * 4 + quad;
            s16x8 ah[2], al[2];
#pragma unroll
            for (int mt = 0; mt < 2; ++mt) {
                int r = wm * 32 + mt * 16 + l16;
                ah[mt] = *(s16x8*)&S[AHo + swzi(r, s)];
                al[mt] = *(s16x8*)&S[ALo + swzi(r, s)];
            }
#pragma unroll
            for (int tt = 0; tt < 4; ++tt) {
                int cc = wn * 64 + tt * 16 + l16;
                s16x8 bh = *(s16x8*)&S[BCHo + swzi(cc, s)];
                s16x8 bl = *(s16x8*)&S[BCLo + swzi(cc, s)];
#pragma unroll
                for (int mt = 0; mt < 2; ++mt) {
                    acc2[mt][tt] = MFMA(ah[mt], bh, acc2[mt][tt]);
                    acc2[mt][tt] = MFMA(ah[mt], bl, acc2[mt][tt]);
                    if (wn == 0) acc2[mt][tt] = MFMA(al[mt], bh, acc2[mt][tt]);
                }
            }
        }

#pragma unroll
        for (int mt = 0; mt < 2; ++mt)
#pragma unroll
            for (int tt = 0; tt < 4; ++tt) {
                int col = wn * 64 + tt * 16 + l16;
#pragma unroll
                for (int r = 0; r < 4; ++r) {
                    int row = rows0 + wm * 32 + mt * 16 + quad * 4 + r;
                    if (row >= M) continue;
                    float v = acc2[mt][tt][r];
                    if (col < 64) PhN[(size_t)row * 64 + col] = f2bf(v + pre_bN[col]);
                    else          QhN[(size_t)row * 64 + (col - 64)] = f2bf(v);
                }
            }
    }
}

// ---------------- launch ----------------

extern "C" void kernel_launch(void* const* d_in, const int* in_sizes, int n_in,
                              void* d_out, int out_size, void* d_ws, size_t ws_size,
                              hipStream_t stream) {
    const float* x      = (const float*)d_in[0];
    const int*   ei     = (const int*)d_in[1];
    const float* pre_w  = (const float*)d_in[2];
    const float* pre_b  = (const float*)d_in[3];
    const float* post_w = (const float*)d_in[4];
    const float* post_b = (const float*)d_in[5];
    const float* lin_w  = (const float*)d_in[6];
    const float* lin_b  = (const float*)d_in[7];

    const int N = in_sizes[0] / 64;
    const int E = in_sizes[1] / 2;
    const int L = in_sizes[2] / (128 * 64);

    const int* srcIdx = ei;
    const int* dstIdx = ei + E;

    char* ws = (char*)d_ws;
    size_t off = 0;
    auto alloc = [&](size_t bytes) {
        void* p = ws + off;
        off += (bytes + 255) & ~(size_t)255;
        return p;
    };
    int*      deg        = (int*)alloc((size_t)N * 4);
    int*      offs       = (int*)alloc((size_t)(N + 1) * 4);
    u16*      srcSorted  = (u16*)alloc((size_t)NBP * CAPS * 2);
    unsigned* edgeTmp    = (unsigned*)alloc((size_t)NBP * CAP * 4);
    int*      bucketCur  = (int*)alloc(NBP * 4);
    float*    lsum       = (float*)alloc(256);
    u16*      WpT_hi     = (u16*)alloc((size_t)L * 128 * 64 * 2);
    u16*      WpT_lo     = (u16*)alloc((size_t)L * 128 * 64 * 2);
    u16*      WT_hi      = (u16*)alloc((size_t)L * 192 * 320 * 2);
    u16*      WT_lo      = (u16*)alloc((size_t)L * 192 * 320 * 2);
    float*    bpp        = (float*)alloc((size_t)L * 64 * 4);
    u16*      Ph         = (u16*)alloc((size_t)N * 64 * 2);
    u16*      Qh         = (u16*)alloc((size_t)N * 64 * 2);
    u16*      AGGh       = (u16*)alloc((size_t)N * 256 * 2);
    float*    hA         = (float*)alloc((size_t)N * 64 * 4);
    float*    hB         = (float*)alloc((size_t)N * 64 * 4);
    (void)ws_size;

    int NB = (N + 255) >> 8;
    int NB1 = (E + EPB3 - 1) / EPB3;
    int gblk = (N + 63) / 64;
    int gblk2 = (N + 127) / 128;

    hipMemsetAsync(bucketCur, 0, NBP * 4, stream);
    hipMemsetAsync(lsum, 0, 4, stream);

    k_pre1<<<NB1 + 449 * L, 512, 0, stream>>>(
        srcIdx, dstIdx, E, bucketCur, edgeTmp,
        pre_w, post_w, post_b, lin_w, lin_b,
        WpT_hi, WpT_lo, WT_hi, WT_lo, bpp, NB1);

    k_pre2<<<NB + gblk, 512, 0, stream>>>(
        edgeTmp, bucketCur, deg, offs, lsum, srcSorted,
        x, WpT_hi, WpT_lo, pre_b, Ph, Qh, N, E, NB);

    const float* hIn = x;
    float* hbuf[2] = {hA, hB};
    for (int l = 0; l < L; ++l) {
        float* hOut = (l == L - 1) ? (float*)d_out : hbuf[l & 1];
        int dn = (l < L - 1) ? 1 : 0;
        int ln = dn ? (l + 1) : 0;
        k_agg<<<(N + 15) / 16, 256, 0, stream>>>(Ph, Qh, offs, deg, srcSorted, AGGh, N);
        k_gemm2<<<gblk2, 512, 0, stream>>>(hIn, AGGh,
                                           WT_hi + (size_t)l * 192 * 320,
                                           WT_lo + (size_t)l * 192 * 320,
                                           bpp + (size_t)l * 64,
                                           deg, lsum, hOut, dn,
                                           WpT_hi + (size_t)ln * 128 * 64,
                                           WpT_lo + (size_t)ln * 128 * 64,
                                           pre_b + (size_t)ln * 64,
                                           Ph, Qh, N);
        hIn = hOut;
    }
}